// Round 3
// baseline (481.758 us; speedup 1.0000x reference)
//
#include <hip/hip_runtime.h>

#define NS_ 100000
#define NW_ 400000
#define NE_ 500000
#define EPB 2048   // elements per scan block

#define SP_BLKS  ((NS_ + 63) / 64)        // 1563 sites_pre blocks
#define HG_BLKS  ((NE_ + 255) / 256)      // 1954 hist blocks per relation
#define SAGE_BLKS (NS_ / 16)              // 6250
#define GAT_BLKS  (NW_ / 16)              // 25000

typedef float f32x4_t __attribute__((ext_vector_type(4)));
typedef unsigned u32x4_t __attribute__((ext_vector_type(4)));

__device__ __forceinline__ float lrelu02(float x) { return x > 0.f ? x : 0.2f * x; }
__device__ __forceinline__ float bf2f(unsigned short u) {
    return __uint_as_float(((unsigned)u) << 16);
}
__device__ __forceinline__ unsigned short f2bf(float f) {
    unsigned u = __float_as_uint(f);
    u += 0x7FFFu + ((u >> 16) & 1u);           // round-to-nearest-even
    return (unsigned short)(u >> 16);
}
__device__ __forceinline__ unsigned pk(float lo, float hi) {
    return (unsigned)f2bf(lo) | ((unsigned)f2bf(hi) << 16);
}
// D = A*B + D, 16x16x32 bf16. a/b = 8 bf16 packed in 4 dwords (k ascending).
// A[m=lane&15][k=(lane>>4)*8+j]; B[k=(lane>>4)*8+j][n=lane&15];
// D: col=lane&15, row=(lane>>4)*4+reg.   (layout HW-verified in rounds 4/5)
__device__ __forceinline__ void mfma_bf16(f32x4_t& acc, u32x4_t a, u32x4_t b) {
    asm volatile("v_mfma_f32_16x16x32_bf16 %0, %1, %2, %0" : "+v"(acc) : "v"(a), "v"(b));
}

// ---------------------------------------------------------------------------
// Prep (single block): vd/vs attention vectors + all weight B-fragments.
// fw : 8 frags  : Wc = Wl_ww + Wr_ww                      (wells dense, K=64)
// fs : 16 frags : kc0-1 Wl_ws (mn), kc2-3 Wr_ws+mean W_ss (sites dense, K=128)
// fsp: 32 frags : W_sw [64,256] for the sites projection   (kc*16+ct)
// ---------------------------------------------------------------------------
__global__ void __launch_bounds__(256)
k_prep(const float* __restrict__ W_sw, const float* __restrict__ att_src,
       const float* __restrict__ att_dst,
       const float* __restrict__ Wl_ww, const float* __restrict__ Wr_ww,
       const float* __restrict__ Wl_ws, const float* __restrict__ Wr_ws,
       const float* __restrict__ W_ss,
       float* __restrict__ vd, float* __restrict__ vs,
       u32x4_t* __restrict__ fw, u32x4_t* __restrict__ fs,
       u32x4_t* __restrict__ fsp)
{
    const int tid = threadIdx.x;
    {   // vd (att_dst) and vs (att_src): v[d*4+h] = sum_c W_sw[d,h*64+c]*att[h,c]
        int d = tid >> 2, h = tid & 3;
        const float4* wp = (const float4*)(W_sw + d * 256 + h * 64);
        const float4* ad = (const float4*)(att_dst + h * 64);
        const float4* as = (const float4*)(att_src + h * 64);
        float accd = 0.f, accs = 0.f;
#pragma unroll
        for (int c = 0; c < 16; ++c) {
            float4 wv = wp[c]; float4 dv = ad[c]; float4 sv = as[c];
            accd += wv.x * dv.x + wv.y * dv.y + wv.z * dv.z + wv.w * dv.w;
            accs += wv.x * sv.x + wv.y * sv.y + wv.z * sv.z + wv.w * sv.w;
        }
        vd[d * 4 + h] = accd;
        vs[d * 4 + h] = accs;
    }
    for (int idx = tid; idx < 512; idx += 256) {
        int f = idx >> 6, lane = idx & 63;
        int kc = f >> 2, ct = f & 3, q = lane >> 4, n = lane & 15;
        int c = ct * 16 + n;
        u32x4_t d;
#pragma unroll
        for (int i = 0; i < 4; ++i) {
            int k = kc * 32 + q * 8 + 2 * i;
            d[i] = pk(Wl_ww[k * 64 + c] + Wr_ww[k * 64 + c],
                      Wl_ww[(k + 1) * 64 + c] + Wr_ww[(k + 1) * 64 + c]);
        }
        fw[idx] = d;
    }
    for (int idx = tid; idx < 1024; idx += 256) {
        int f = idx >> 6, lane = idx & 63;
        int kc = f >> 2, ct = f & 3, q = lane >> 4, n = lane & 15;
        int c = ct * 16 + n;
        u32x4_t d;
#pragma unroll
        for (int i = 0; i < 4; ++i) {
            int k = kc * 32 + q * 8 + 2 * i;
            float lo, hi;
            if (k < 64) {
                lo = Wl_ws[k * 64 + c];
                hi = Wl_ws[(k + 1) * 64 + c];
            } else {
                int kk = k - 64;
                lo = Wr_ws[kk * 64 + c] + 0.25f * (W_ss[kk * 256 + c] + W_ss[kk * 256 + 64 + c] +
                                                   W_ss[kk * 256 + 128 + c] + W_ss[kk * 256 + 192 + c]);
                hi = Wr_ws[(kk + 1) * 64 + c] + 0.25f * (W_ss[(kk + 1) * 256 + c] + W_ss[(kk + 1) * 256 + 64 + c] +
                                                         W_ss[(kk + 1) * 256 + 128 + c] + W_ss[(kk + 1) * 256 + 192 + c]);
            }
            d[i] = pk(lo, hi);
        }
        fs[idx] = d;
    }
    for (int idx = tid; idx < 2048; idx += 256) {
        int f = idx >> 6, lane = idx & 63;
        int kc = f >> 4, ct = f & 15, q = lane >> 4, n = lane & 15;
        int c = ct * 16 + n;
        u32x4_t d;
#pragma unroll
        for (int i = 0; i < 4; ++i) {
            int k = kc * 32 + q * 8 + 2 * i;
            d[i] = pk(W_sw[k * 256 + c], W_sw[(k + 1) * 256 + c]);
        }
        fsp[idx] = d;
    }
}

// ---------------------------------------------------------------------------
// MERGED launch 1: sites projection (MFMA-heavy) UNION edge histogram
// (atomic/latency-bound). Co-residency hides each other's stalls.
// ---------------------------------------------------------------------------
#define SP_PAD 264   // 256 + 8 ushorts row pad (bank rotation for b16 stores)
__global__ void __launch_bounds__(256)
k_main1(const float* __restrict__ x_sites, const u32x4_t* __restrict__ fsp,
        const float* __restrict__ vs, unsigned short* __restrict__ xs,
        float* __restrict__ al_s,
        const int* __restrict__ d1, int* __restrict__ h1,
        const int* __restrict__ d2, int* __restrict__ h2)
{
    __shared__ float smem1[8704];   // stg: 4*16*264 ushorts (8448 f) + vsl 256 f
    const int tid = threadIdx.x;
    const int bid = blockIdx.x;
    if (bid >= SP_BLKS) {
        // ---- histogram body ----
        int hb = bid - SP_BLKS;
        int rel = hb / HG_BLKS;
        int e = (hb % HG_BLKS) * 256 + tid;
        if (e < NE_) {
            if (rel == 0) atomicAdd(&h1[d1[e]], 1);
            else          atomicAdd(&h2[d2[e]], 1);
        }
        return;
    }
    // ---- sites projection body (round-1 k_sites_pre, LDS carved) ----
    unsigned short* stg = (unsigned short*)smem1;       // [4][16*SP_PAD]
    float* vsl = smem1 + 8448 / 2 * 0 + 8448;           // wrong-proof: see below
    vsl = smem1 + 8448;                                  // 8448 floats of stg (16896 us)
    vsl[tid] = vs[tid];
    __syncthreads();
    const int wave = __builtin_amdgcn_readfirstlane(tid >> 6);
    const int lane = tid & 63, q = lane >> 4, n = lane & 15;
    const int sbase = bid * 64 + wave * 16;
    const int srow = min(sbase + n, NS_ - 1);
    const float* xr = x_sites + (size_t)srow * 64 + q * 8;
    float4 x0 = *(const float4*)(xr);
    float4 x1 = *(const float4*)(xr + 4);
    float4 x2 = *(const float4*)(xr + 32);
    float4 x3 = *(const float4*)(xr + 36);
    u32x4_t am0 = { pk(x0.x, x0.y), pk(x0.z, x0.w), pk(x1.x, x1.y), pk(x1.z, x1.w) };
    u32x4_t am1 = { pk(x2.x, x2.y), pk(x2.z, x2.w), pk(x3.x, x3.y), pk(x3.z, x3.w) };
    // fused al_s partials over this lane's 16 k-values (fp32 x, exact path)
    float pa[4];
#pragma unroll
    for (int h = 0; h < 4; ++h) {
        const float* v0 = &vsl[(q * 8) * 4 + h];
        const float* v1 = &vsl[(32 + q * 8) * 4 + h];
        pa[h] = x0.x * v0[0]  + x0.y * v0[4]  + x0.z * v0[8]  + x0.w * v0[12]
              + x1.x * v0[16] + x1.y * v0[20] + x1.z * v0[24] + x1.w * v0[28]
              + x2.x * v1[0]  + x2.y * v1[4]  + x2.z * v1[8]  + x2.w * v1[12]
              + x3.x * v1[16] + x3.y * v1[20] + x3.z * v1[24] + x3.w * v1[28];
    }
#pragma unroll
    for (int h = 0; h < 4; ++h) {
        pa[h] += __shfl_xor(pa[h], 16, 64);
        pa[h] += __shfl_xor(pa[h], 32, 64);
    }
    if (q == 0 && sbase + n < NS_)
        *(float4*)(al_s + (size_t)(sbase + n) * 4) = make_float4(pa[0], pa[1], pa[2], pa[3]);

    f32x4_t acc[16];
#pragma unroll
    for (int ct = 0; ct < 16; ++ct) acc[ct] = (f32x4_t){0, 0, 0, 0};
    asm volatile("s_nop 3" : "+v"(am0), "+v"(am1));
#pragma unroll
    for (int ct = 0; ct < 16; ++ct) mfma_bf16(acc[ct], am0, fsp[ct * 64 + lane]);
#pragma unroll
    for (int ct = 0; ct < 16; ++ct) mfma_bf16(acc[ct], am1, fsp[(16 + ct) * 64 + lane]);
    asm volatile("s_nop 7\n\ts_nop 7" ::: "memory");
    // stage to LDS (row = local site, col = channel), then coalesced copy-out
    unsigned short* ss = stg + wave * (16 * SP_PAD);
#pragma unroll
    for (int ct = 0; ct < 16; ++ct)
#pragma unroll
        for (int reg = 0; reg < 4; ++reg)
            ss[(q * 4 + reg) * SP_PAD + ct * 16 + n] = f2bf(acc[ct][reg]);
    __builtin_amdgcn_s_waitcnt(0);   // drain lgkm before wave-local readback
#pragma unroll
    for (int i = 0; i < 8; ++i) {
        int g = i * 64 + lane;
        int r = g >> 5, c = g & 31;
        if (sbase + r < NS_) {
            u32x4_t v = *(const u32x4_t*)(ss + r * SP_PAD + c * 8);
            *(u32x4_t*)(xs + (size_t)(sbase + r) * 256 + c * 8) = v;
        }
    }
}

// ---------------------------------------------------------------------------
// CSR build: 3-phase scan -> scatter (relations merged per launch)
// ---------------------------------------------------------------------------
__global__ void __launch_bounds__(256)
k_scan1_2(const int* __restrict__ h1, int n1, int* __restrict__ b1, int nb1,
          const int* __restrict__ h2, int n2, int* __restrict__ b2)
{
    __shared__ int red[256];
    const int tid = threadIdx.x;
    const int bx = blockIdx.x;
    const int* hist; int n; int* bsum; int blk;
    if (bx < nb1) { hist = h1; n = n1; bsum = b1; blk = bx; }
    else          { hist = h2; n = n2; bsum = b2; blk = bx - nb1; }
    int base = blk * EPB + tid * 8;
    int s = 0;
#pragma unroll
    for (int i = 0; i < 8; ++i) { int idx = base + i; if (idx < n) s += hist[idx]; }
    red[tid] = s;
    __syncthreads();
    for (int off = 128; off > 0; off >>= 1) {
        if (tid < off) red[tid] += red[tid + off];
        __syncthreads();
    }
    if (tid == 0) bsum[blk] = red[0];
}

__global__ void __launch_bounds__(256)
k_scan2_2(int* __restrict__ b1, int nb1, int* __restrict__ b2, int nb2)
{
    __shared__ int sh[256];
    const int tid = threadIdx.x;
    int* bsum = blockIdx.x == 0 ? b1 : b2;
    int nb = blockIdx.x == 0 ? nb1 : nb2;
    sh[tid] = (tid < nb) ? bsum[tid] : 0;
    __syncthreads();
    for (int off = 1; off < 256; off <<= 1) {
        int u = (tid >= off) ? sh[tid - off] : 0;
        __syncthreads();
        sh[tid] += u;
        __syncthreads();
    }
    if (tid < nb) bsum[tid] = (tid == 0) ? 0 : sh[tid - 1];
}

__global__ void __launch_bounds__(256)
k_scan3_2(const int* __restrict__ h1, int n1, const int* __restrict__ b1,
          int* __restrict__ rp1, int* __restrict__ cu1, int nb1,
          const int* __restrict__ h2, int n2, const int* __restrict__ b2,
          int* __restrict__ rp2, int* __restrict__ cu2)
{
    __shared__ int tsum[256];
    const int tid = threadIdx.x;
    const int bx = blockIdx.x;
    const int* hist; int n; const int* bsum; int* rowptr; int* cursor; int blk;
    if (bx < nb1) { hist = h1; n = n1; bsum = b1; rowptr = rp1; cursor = cu1; blk = bx; }
    else          { hist = h2; n = n2; bsum = b2; rowptr = rp2; cursor = cu2; blk = bx - nb1; }
    int base = blk * EPB + tid * 8;
    int v[8]; int s = 0;
#pragma unroll
    for (int i = 0; i < 8; ++i) {
        int idx = base + i;
        v[i] = (idx < n) ? hist[idx] : 0;
        s += v[i];
    }
    tsum[tid] = s;
    __syncthreads();
    for (int off = 1; off < 256; off <<= 1) {
        int u = (tid >= off) ? tsum[tid - off] : 0;
        __syncthreads();
        tsum[tid] += u;
        __syncthreads();
    }
    int texcl = tsum[tid] - s;
    int run = bsum[blk] + texcl;
#pragma unroll
    for (int i = 0; i < 8; ++i) {
        int idx = base + i;
        if (idx < n) { rowptr[idx] = run; cursor[idx] = run; run += v[i]; }
    }
    if (blk == 0 && tid == 0) rowptr[n] = NE_;
}

__global__ void __launch_bounds__(256)
k_scatter2(const int* __restrict__ s1, const int* __restrict__ d1,
           int* __restrict__ c1, int* __restrict__ o1,
           const int* __restrict__ s2, const int* __restrict__ d2,
           int* __restrict__ c2, int* __restrict__ o2)
{
    int e = blockIdx.x * 256 + threadIdx.x;
    if (e >= NE_) return;
    if (blockIdx.y == 0) { int p = atomicAdd(&c1[d1[e]], 1); o1[p] = s1[e]; }
    else                 { int p = atomicAdd(&c2[d2[e]], 1); o2[p] = s2[e]; }
}

// ---------------------------------------------------------------------------
// MERGED launch 6: sage-sites UNION gat-wells. Both latency-bound gathers;
// co-resident waves hide each other's memory latency.
// gat body = round-1 structure (gather projected xs, msg in-register) with
// packed-bf16 LDS A-tiles + rotation swizzle (col' = (2p + 8*row)&31) so
// ds_read_b128 quarter-waves are 2-way (free) instead of 8-way.
// ---------------------------------------------------------------------------
__global__ void __launch_bounds__(256)
k_main6(const float* __restrict__ x_sites, const float* __restrict__ x_wells,
        const int* __restrict__ rp_ws, const int* __restrict__ csr_ws,
        const u32x4_t* __restrict__ fs, const float* __restrict__ bl_ws,
        const float* __restrict__ b_ss, const float* __restrict__ Wsit,
        const float* __restrict__ bsit,
        const float* __restrict__ vd, const int* __restrict__ rp_sw,
        const int* __restrict__ csr_sw, const float* __restrict__ al_s,
        const unsigned short* __restrict__ xs, const float* __restrict__ b_sw,
        const float* __restrict__ bl_ww, const u32x4_t* __restrict__ fw,
        const float* __restrict__ Wg, const float* __restrict__ bg,
        float* __restrict__ out)
{
    __shared__ float smem[2400];
    const int tid = threadIdx.x;
    const int bid = blockIdx.x;

    if (bid < SAGE_BLKS) {
        // ================= SAGE sites body =================
        unsigned* mnB = (unsigned*)smem;           // [16][36]
        unsigned* xB  = (unsigned*)(smem + 576);   // [16][36]
        float* dl     = smem + 1152;               // [16][68]
        float* biasl  = smem + 2240;               // [64]
        float* wsl    = smem + 2304;               // [64]
        float* res    = smem + 2368;               // [16]
        if (tid < 64) { biasl[tid] = bl_ws[tid] + b_ss[tid]; wsl[tid] = Wsit[tid]; }
        const int sl = tid >> 4, p = tid & 15;
        const int s = bid * 16 + sl;
        const int r0 = rp_ws[s], r1 = rp_ws[s + 1];
        float4 m4 = {0.f, 0.f, 0.f, 0.f};
        for (int j = r0; j < r1; ++j) {
            int wsrc = csr_ws[j];
            float4 xv = ((const float4*)(x_wells + (size_t)wsrc * 64))[p];
            m4.x += xv.x; m4.y += xv.y; m4.z += xv.z; m4.w += xv.w;
        }
        if (r1 > r0) {
            float rc = 1.f / (float)(r1 - r0);
            m4.x *= rc; m4.y *= rc; m4.z *= rc; m4.w *= rc;
        }
        {
            int c0 = (2 * p + 8 * sl) & 31;
            mnB[sl * 36 + c0]     = pk(m4.x, m4.y);
            mnB[sl * 36 + c0 + 1] = pk(m4.z, m4.w);
            float4 xv = *(const float4*)(x_sites + (size_t)s * 64 + 4 * p);
            xB[sl * 36 + c0]     = pk(xv.x, xv.y);
            xB[sl * 36 + c0 + 1] = pk(xv.z, xv.w);
        }
        __syncthreads();
        const int wave = __builtin_amdgcn_readfirstlane(tid >> 6);
        const int lane = tid & 63, q = lane >> 4, n = lane & 15;
        const int b0 = (4 * q + 8 * n) & 31;
        const int b1 = (16 + 4 * q + 8 * n) & 31;
        u32x4_t am0 = *(const u32x4_t*)&mnB[n * 36 + b0];
        u32x4_t am1 = *(const u32x4_t*)&mnB[n * 36 + b1];
        u32x4_t ax0 = *(const u32x4_t*)&xB[n * 36 + b0];
        u32x4_t ax1 = *(const u32x4_t*)&xB[n * 36 + b1];
        f32x4_t acc = {0, 0, 0, 0};
        asm volatile("s_nop 3" : "+v"(am0), "+v"(am1), "+v"(ax0), "+v"(ax1), "+v"(acc));
        mfma_bf16(acc, am0, fs[wave * 64 + lane]);
        mfma_bf16(acc, am1, fs[(4 + wave) * 64 + lane]);
        mfma_bf16(acc, ax0, fs[(8 + wave) * 64 + lane]);
        mfma_bf16(acc, ax1, fs[(12 + wave) * 64 + lane]);
        asm volatile("s_nop 7\n\ts_nop 7" : "+v"(acc));
#pragma unroll
        for (int reg = 0; reg < 4; ++reg)
            dl[(q * 4 + reg) * 68 + wave * 16 + n] = acc[reg];
        __syncthreads();
        const int c0 = 4 * p;
        float4 dv = *(const float4*)&dl[sl * 68 + c0];
        float t0 = dv.x + biasl[c0];
        float t1 = dv.y + biasl[c0 + 1];
        float t2 = dv.z + biasl[c0 + 2];
        float t3 = dv.w + biasl[c0 + 3];
        float pr = fmaxf(t0, 0.f) * wsl[c0] + fmaxf(t1, 0.f) * wsl[c0 + 1] +
                   fmaxf(t2, 0.f) * wsl[c0 + 2] + fmaxf(t3, 0.f) * wsl[c0 + 3];
        pr += __shfl_xor(pr, 1, 64);
        pr += __shfl_xor(pr, 2, 64);
        pr += __shfl_xor(pr, 4, 64);
        pr += __shfl_xor(pr, 8, 64);
        if (p == 0) res[sl] = pr + bsit[0];
        __syncthreads();
        if (tid < 16) {
            float v = res[tid];
            out[(size_t)NW_ + bid * 16 + tid] = v > 0.f ? v : 0.01f * v;
        }
        return;
    }

    // ================= GAT wells body =================
    {
        const int gb = bid - SAGE_BLKS;
        float* vdl    = smem;                       // [16][17]
        unsigned* xwB = (unsigned*)(smem + 272);    // [16][36]
        float* dl     = smem + 848;                 // [16][68]
        float* biasl  = smem + 1936;                // [64]
        float* wgl    = smem + 2000;                // [64]
        float* res    = smem + 2064;                // [16]
        vdl[(tid >> 4) * 17 + (tid & 15)] = vd[tid];
        if (tid < 64) { biasl[tid] = b_sw[tid] + bl_ww[tid]; wgl[tid] = Wg[tid]; }
        __syncthreads();
        const int wl = tid >> 4, p = tid & 15;
        const int w = gb * 16 + wl;
        const int r0 = rp_sw[w], r1 = rp_sw[w + 1];
        float h0, h1, h2, h3;
        {
            float4 xv = *(const float4*)(x_wells + (size_t)w * 64 + 4 * p);
            int c0 = (2 * p + 8 * wl) & 31;
            xwB[wl * 36 + c0]     = pk(xv.x, xv.y);
            xwB[wl * 36 + c0 + 1] = pk(xv.z, xv.w);
            const float* vp = &vdl[p * 17];
            h0 = xv.x * vp[0] + xv.y * vp[4] + xv.z * vp[8]  + xv.w * vp[12];
            h1 = xv.x * vp[1] + xv.y * vp[5] + xv.z * vp[9]  + xv.w * vp[13];
            h2 = xv.x * vp[2] + xv.y * vp[6] + xv.z * vp[10] + xv.w * vp[14];
            h3 = xv.x * vp[3] + xv.y * vp[7] + xv.z * vp[11] + xv.w * vp[15];
        }
#pragma unroll
        for (int off = 1; off < 16; off <<= 1) {
            h0 += __shfl_xor(h0, off, 64);
            h1 += __shfl_xor(h1, off, 64);
            h2 += __shfl_xor(h2, off, 64);
            h3 += __shfl_xor(h3, off, 64);
        }
        float den0 = 0, den1 = 0, den2 = 0, den3 = 0;
        float n0[4] = {0, 0, 0, 0}, n1[4] = {0, 0, 0, 0};
        float n2[4] = {0, 0, 0, 0}, n3[4] = {0, 0, 0, 0};
        for (int j = r0; j < r1; ++j) {
            int s = csr_sw[j];
            float4 as = ((const float4*)al_s)[s];
            float e0 = __expf(lrelu02(as.x + h0));
            float e1 = __expf(lrelu02(as.y + h1));
            float e2 = __expf(lrelu02(as.z + h2));
            float e3 = __expf(lrelu02(as.w + h3));
            den0 += e0; den1 += e1; den2 += e2; den3 += e3;
            const unsigned short* xr = xs + (size_t)s * 256 + 4 * p;
            ushort4 u0 = *(const ushort4*)(xr);
            ushort4 u1 = *(const ushort4*)(xr + 64);
            ushort4 u2 = *(const ushort4*)(xr + 128);
            ushort4 u3 = *(const ushort4*)(xr + 192);
            n0[0] += e0 * bf2f(u0.x); n0[1] += e0 * bf2f(u0.y); n0[2] += e0 * bf2f(u0.z); n0[3] += e0 * bf2f(u0.w);
            n1[0] += e1 * bf2f(u1.x); n1[1] += e1 * bf2f(u1.y); n1[2] += e1 * bf2f(u1.z); n1[3] += e1 * bf2f(u1.w);
            n2[0] += e2 * bf2f(u2.x); n2[1] += e2 * bf2f(u2.y); n2[2] += e2 * bf2f(u2.z); n2[3] += e2 * bf2f(u2.w);
            n3[0] += e3 * bf2f(u3.x); n3[1] += e3 * bf2f(u3.y); n3[2] += e3 * bf2f(u3.z); n3[3] += e3 * bf2f(u3.w);
        }
        const int c0 = 4 * p;
        float tmsg[4];
        if (r1 > r0) {
            float i0 = 0.25f / den0, i1 = 0.25f / den1, i2 = 0.25f / den2, i3 = 0.25f / den3;
#pragma unroll
            for (int i = 0; i < 4; ++i)
                tmsg[i] = n0[i] * i0 + n1[i] * i1 + n2[i] * i2 + n3[i] * i3 + biasl[c0 + i];
        } else {
#pragma unroll
            for (int i = 0; i < 4; ++i) tmsg[i] = biasl[c0 + i];
        }
        __syncthreads();   // xwB fully staged
        const int wave = __builtin_amdgcn_readfirstlane(tid >> 6);
        const int lane = tid & 63, q = lane >> 4, n = lane & 15;
        const int b0 = (4 * q + 8 * n) & 31;
        const int b1 = (16 + 4 * q + 8 * n) & 31;
        u32x4_t ax0 = *(const u32x4_t*)&xwB[n * 36 + b0];
        u32x4_t ax1 = *(const u32x4_t*)&xwB[n * 36 + b1];
        f32x4_t acc = {0, 0, 0, 0};
        asm volatile("s_nop 3" : "+v"(ax0), "+v"(ax1), "+v"(acc));
        mfma_bf16(acc, ax0, fw[wave * 64 + lane]);
        mfma_bf16(acc, ax1, fw[(4 + wave) * 64 + lane]);
        asm volatile("s_nop 7\n\ts_nop 7" : "+v"(acc));
#pragma unroll
        for (int reg = 0; reg < 4; ++reg)
            dl[(q * 4 + reg) * 68 + wave * 16 + n] = acc[reg];
        __syncthreads();
        float4 dv = *(const float4*)&dl[wl * 68 + c0];
        float t0 = tmsg[0] + dv.x;
        float t1 = tmsg[1] + dv.y;
        float t2 = tmsg[2] + dv.z;
        float t3 = tmsg[3] + dv.w;
        float pr = fmaxf(t0, 0.f) * wgl[c0] + fmaxf(t1, 0.f) * wgl[c0 + 1] +
                   fmaxf(t2, 0.f) * wgl[c0 + 2] + fmaxf(t3, 0.f) * wgl[c0 + 3];
        pr += __shfl_xor(pr, 1, 64);
        pr += __shfl_xor(pr, 2, 64);
        pr += __shfl_xor(pr, 4, 64);
        pr += __shfl_xor(pr, 8, 64);
        if (p == 0) res[wl] = pr + bg[0];
        __syncthreads();
        if (tid < 16) {
            float v = res[tid];
            out[gb * 16 + tid] = v > 0.f ? v : 0.01f * v;
        }
    }
}

// ---------------------------------------------------------------------------
extern "C" void kernel_launch(void* const* d_in, const int* in_sizes, int n_in,
                              void* d_out, int out_size, void* d_ws, size_t ws_size,
                              hipStream_t stream)
{
    const float* x_sites    = (const float*)d_in[0];
    const float* x_wells    = (const float*)d_in[1];
    const int*   e_sw_src   = (const int*)d_in[2];
    const int*   e_sw_dst   = (const int*)d_in[3];
    const int*   e_ws_src   = (const int*)d_in[4];
    const int*   e_ws_dst   = (const int*)d_in[5];
    const float* W_sw       = (const float*)d_in[6];
    const float* att_src_sw = (const float*)d_in[7];
    const float* att_dst_sw = (const float*)d_in[8];
    const float* b_sw       = (const float*)d_in[9];
    const float* Wl_ws      = (const float*)d_in[10];
    const float* bl_ws      = (const float*)d_in[11];
    const float* Wr_ws      = (const float*)d_in[12];
    const float* W_ss       = (const float*)d_in[13];
    // d_in[14], d_in[15]: att_*_ss cancel (softmax over single self edge == 1)
    const float* b_ss       = (const float*)d_in[16];
    const float* Wl_ww      = (const float*)d_in[17];
    const float* bl_ww      = (const float*)d_in[18];
    const float* Wr_ww      = (const float*)d_in[19];
    const float* Wg         = (const float*)d_in[20];
    const float* bg         = (const float*)d_in[21];
    const float* Wsit       = (const float*)d_in[22];
    const float* bsit       = (const float*)d_in[23];
    float* out = (float*)d_out;

    // workspace layout
    unsigned short* xs = (unsigned short*)d_ws;            // NS*256 bf16
    float* al_s = (float*)(xs + (size_t)NS_ * 256);        // NS*4
    float* vd   = al_s + (size_t)NS_ * 4;                  // 256
    float* vs   = vd + 256;                                // 256
    u32x4_t* fw = (u32x4_t*)(vs + 256);                    // 512  (8 KB)
    u32x4_t* fs = fw + 512;                                // 1024 (16 KB)
    u32x4_t* fsp= fs + 1024;                               // 2048 (32 KB)
    int* ip     = (int*)(fsp + 2048);
    int* h_sw   = ip;                                      // NW   (zeroed)
    int* h_ws   = h_sw + NW_;                              // NS   (zeroed, adjacent)
    int* rp_sw  = h_ws + NS_;                              // NW+4
    int* cur_sw = rp_sw + NW_ + 4;                         // NW
    int* csr_sw = cur_sw + NW_;                            // E
    int* bs_sw  = csr_sw + NE_;                            // 256
    int* rp_ws  = bs_sw + 256;                             // NS+4
    int* cur_ws = rp_ws + NS_ + 4;                         // NS
    int* csr_ws = cur_ws + NS_;                            // E
    int* bs_ws  = csr_ws + NE_;                            // 256

    hipMemsetAsync(h_sw, 0, (size_t)(NW_ + NS_) * sizeof(int), stream);

    const int egrid = HG_BLKS;
    const int nb_sw = (NW_ + EPB - 1) / EPB;   // 196
    const int nb_ws = (NS_ + EPB - 1) / EPB;   // 49

    hipLaunchKernelGGL(k_prep, dim3(1), dim3(256), 0, stream,
                       W_sw, att_src_sw, att_dst_sw, Wl_ww, Wr_ww, Wl_ws, Wr_ws, W_ss,
                       vd, vs, fw, fs, fsp);

    // merged: sites projection + histogram
    hipLaunchKernelGGL(k_main1, dim3(SP_BLKS + 2 * HG_BLKS), dim3(256), 0, stream,
                       x_sites, fsp, vs, xs, al_s,
                       e_sw_dst, h_sw, e_ws_dst, h_ws);

    hipLaunchKernelGGL(k_scan1_2, dim3(nb_sw + nb_ws), dim3(256), 0, stream,
                       h_sw, NW_, bs_sw, nb_sw, h_ws, NS_, bs_ws);
    hipLaunchKernelGGL(k_scan2_2, dim3(2), dim3(256), 0, stream,
                       bs_sw, nb_sw, bs_ws, nb_ws);
    hipLaunchKernelGGL(k_scan3_2, dim3(nb_sw + nb_ws), dim3(256), 0, stream,
                       h_sw, NW_, bs_sw, rp_sw, cur_sw, nb_sw,
                       h_ws, NS_, bs_ws, rp_ws, cur_ws);
    hipLaunchKernelGGL(k_scatter2, dim3(egrid, 2), dim3(256), 0, stream,
                       e_sw_src, e_sw_dst, cur_sw, csr_sw,
                       e_ws_src, e_ws_dst, cur_ws, csr_ws);

    // merged: sage-sites + gat-wells
    hipLaunchKernelGGL(k_main6, dim3(SAGE_BLKS + GAT_BLKS), dim3(256), 0, stream,
                       x_sites, x_wells, rp_ws, csr_ws, fs, bl_ws, b_ss, Wsit, bsit,
                       vd, rp_sw, csr_sw, al_s, xs, b_sw, bl_ww, fw, Wg, bg, out);
}

// Round 4
// 478.908 us; speedup vs baseline: 1.0060x; 1.0060x over previous
//
#include <hip/hip_runtime.h>

#define NS_ 100000
#define NW_ 400000
#define NE_ 500000
#define EPB 2048   // elements per scan block

typedef float f32x4_t __attribute__((ext_vector_type(4)));
typedef unsigned u32x4_t __attribute__((ext_vector_type(4)));

__device__ __forceinline__ float lrelu02(float x) { return x > 0.f ? x : 0.2f * x; }
__device__ __forceinline__ float bf2f(unsigned short u) {
    return __uint_as_float(((unsigned)u) << 16);
}
__device__ __forceinline__ float lo16(unsigned u) { return __uint_as_float(u << 16); }
__device__ __forceinline__ float hi16(unsigned u) { return __uint_as_float(u & 0xFFFF0000u); }
__device__ __forceinline__ unsigned short f2bf(float f) {
    unsigned u = __float_as_uint(f);
    u += 0x7FFFu + ((u >> 16) & 1u);           // round-to-nearest-even
    return (unsigned short)(u >> 16);
}
__device__ __forceinline__ unsigned pk(float lo, float hi) {
    return (unsigned)f2bf(lo) | ((unsigned)f2bf(hi) << 16);
}
// D = A*B + D, 16x16x32 bf16. a/b = 8 bf16 packed in 4 dwords (k ascending).
// A[m=lane&15][k=(lane>>4)*8+j]; B[k=(lane>>4)*8+j][n=lane&15];
// D: col=lane&15, row=(lane>>4)*4+reg.   (layout HW-verified earlier)
__device__ __forceinline__ void mfma_bf16(f32x4_t& acc, u32x4_t a, u32x4_t b) {
    asm volatile("v_mfma_f32_16x16x32_bf16 %0, %1, %2, %0" : "+v"(acc) : "v"(a), "v"(b));
}

// ---------------------------------------------------------------------------
// Prep (single block): vd/vs attention vectors + all weight B-fragments.
// fw : 8 frags  : Wc = Wl_ww + Wr_ww                      (wells dense, K=64)
// fs : 16 frags : kc0-1 Wl_ws (mn), kc2-3 Wr_ws+mean W_ss (sites dense, K=128)
// fsp: 32 frags : W_sw [64,256] for the sites projection   (kc*16+ct)
// ---------------------------------------------------------------------------
__global__ void __launch_bounds__(256)
k_prep(const float* __restrict__ W_sw, const float* __restrict__ att_src,
       const float* __restrict__ att_dst,
       const float* __restrict__ Wl_ww, const float* __restrict__ Wr_ww,
       const float* __restrict__ Wl_ws, const float* __restrict__ Wr_ws,
       const float* __restrict__ W_ss,
       float* __restrict__ vd, float* __restrict__ vs,
       u32x4_t* __restrict__ fw, u32x4_t* __restrict__ fs,
       u32x4_t* __restrict__ fsp)
{
    const int tid = threadIdx.x;
    {   // vd (att_dst) and vs (att_src): v[d*4+h] = sum_c W_sw[d,h*64+c]*att[h,c]
        int d = tid >> 2, h = tid & 3;
        const float4* wp = (const float4*)(W_sw + d * 256 + h * 64);
        const float4* ad = (const float4*)(att_dst + h * 64);
        const float4* as = (const float4*)(att_src + h * 64);
        float accd = 0.f, accs = 0.f;
#pragma unroll
        for (int c = 0; c < 16; ++c) {
            float4 wv = wp[c]; float4 dv = ad[c]; float4 sv = as[c];
            accd += wv.x * dv.x + wv.y * dv.y + wv.z * dv.z + wv.w * dv.w;
            accs += wv.x * sv.x + wv.y * sv.y + wv.z * sv.z + wv.w * sv.w;
        }
        vd[d * 4 + h] = accd;
        vs[d * 4 + h] = accs;
    }
    for (int idx = tid; idx < 512; idx += 256) {
        int f = idx >> 6, lane = idx & 63;
        int kc = f >> 2, ct = f & 3, q = lane >> 4, n = lane & 15;
        int c = ct * 16 + n;
        u32x4_t d;
#pragma unroll
        for (int i = 0; i < 4; ++i) {
            int k = kc * 32 + q * 8 + 2 * i;
            d[i] = pk(Wl_ww[k * 64 + c] + Wr_ww[k * 64 + c],
                      Wl_ww[(k + 1) * 64 + c] + Wr_ww[(k + 1) * 64 + c]);
        }
        fw[idx] = d;
    }
    for (int idx = tid; idx < 1024; idx += 256) {
        int f = idx >> 6, lane = idx & 63;
        int kc = f >> 2, ct = f & 3, q = lane >> 4, n = lane & 15;
        int c = ct * 16 + n;
        u32x4_t d;
#pragma unroll
        for (int i = 0; i < 4; ++i) {
            int k = kc * 32 + q * 8 + 2 * i;
            float lo, hi;
            if (k < 64) {
                lo = Wl_ws[k * 64 + c];
                hi = Wl_ws[(k + 1) * 64 + c];
            } else {
                int kk = k - 64;
                lo = Wr_ws[kk * 64 + c] + 0.25f * (W_ss[kk * 256 + c] + W_ss[kk * 256 + 64 + c] +
                                                   W_ss[kk * 256 + 128 + c] + W_ss[kk * 256 + 192 + c]);
                hi = Wr_ws[(kk + 1) * 64 + c] + 0.25f * (W_ss[(kk + 1) * 256 + c] + W_ss[(kk + 1) * 256 + 64 + c] +
                                                         W_ss[(kk + 1) * 256 + 128 + c] + W_ss[(kk + 1) * 256 + 192 + c]);
            }
            d[i] = pk(lo, hi);
        }
        fs[idx] = d;
    }
    for (int idx = tid; idx < 2048; idx += 256) {
        int f = idx >> 6, lane = idx & 63;
        int kc = f >> 4, ct = f & 15, q = lane >> 4, n = lane & 15;
        int c = ct * 16 + n;
        u32x4_t d;
#pragma unroll
        for (int i = 0; i < 4; ++i) {
            int k = kc * 32 + q * 8 + 2 * i;
            d[i] = pk(W_sw[k * 256 + c], W_sw[(k + 1) * 256 + c]);
        }
        fsp[idx] = d;
    }
}

// ---------------------------------------------------------------------------
// Sites projection via MFMA: xs(bf16, PERMUTED [s][p][h*4+i]) = x_sites@W_sw,
// plus fused al_s = x_sites @ vs. Permutation: channel c=h*64+4p+i stored at
// ushort index p*16 + h*4 + i, so the gather reads 2x16B contiguous per lane.
// ---------------------------------------------------------------------------
#define SP_PAD 264   // 256 + 8 ushorts row pad (bank rotation for b16 stores)
__global__ void __launch_bounds__(256)
k_sites_pre(const float* __restrict__ x_sites, const u32x4_t* __restrict__ fsp,
            const float* __restrict__ vs, unsigned short* __restrict__ xs,
            float* __restrict__ al_s)
{
    __shared__ unsigned short stg[4][16 * SP_PAD];
    __shared__ float vsl[256];
    const int tid = threadIdx.x;
    vsl[tid] = vs[tid];
    __syncthreads();
    const int wave = __builtin_amdgcn_readfirstlane(tid >> 6);
    const int lane = tid & 63, q = lane >> 4, n = lane & 15;
    const int sbase = blockIdx.x * 64 + wave * 16;
    const int srow = min(sbase + n, NS_ - 1);
    const float* xr = x_sites + (size_t)srow * 64 + q * 8;
    float4 x0 = *(const float4*)(xr);
    float4 x1 = *(const float4*)(xr + 4);
    float4 x2 = *(const float4*)(xr + 32);
    float4 x3 = *(const float4*)(xr + 36);
    u32x4_t am0 = { pk(x0.x, x0.y), pk(x0.z, x0.w), pk(x1.x, x1.y), pk(x1.z, x1.w) };
    u32x4_t am1 = { pk(x2.x, x2.y), pk(x2.z, x2.w), pk(x3.x, x3.y), pk(x3.z, x3.w) };
    // fused al_s partials over this lane's 16 k-values (fp32 x, exact path)
    float pa[4];
#pragma unroll
    for (int h = 0; h < 4; ++h) {
        const float* v0 = &vsl[(q * 8) * 4 + h];
        const float* v1 = &vsl[(32 + q * 8) * 4 + h];
        pa[h] = x0.x * v0[0]  + x0.y * v0[4]  + x0.z * v0[8]  + x0.w * v0[12]
              + x1.x * v0[16] + x1.y * v0[20] + x1.z * v0[24] + x1.w * v0[28]
              + x2.x * v1[0]  + x2.y * v1[4]  + x2.z * v1[8]  + x2.w * v1[12]
              + x3.x * v1[16] + x3.y * v1[20] + x3.z * v1[24] + x3.w * v1[28];
    }
#pragma unroll
    for (int h = 0; h < 4; ++h) {
        pa[h] += __shfl_xor(pa[h], 16, 64);
        pa[h] += __shfl_xor(pa[h], 32, 64);
    }
    if (q == 0 && sbase + n < NS_)
        *(float4*)(al_s + (size_t)(sbase + n) * 4) = make_float4(pa[0], pa[1], pa[2], pa[3]);

    f32x4_t acc[16];
#pragma unroll
    for (int ct = 0; ct < 16; ++ct) acc[ct] = (f32x4_t){0, 0, 0, 0};
    asm volatile("s_nop 3" : "+v"(am0), "+v"(am1));
#pragma unroll
    for (int ct = 0; ct < 16; ++ct) mfma_bf16(acc[ct], am0, fsp[ct * 64 + lane]);
#pragma unroll
    for (int ct = 0; ct < 16; ++ct) mfma_bf16(acc[ct], am1, fsp[(16 + ct) * 64 + lane]);
    asm volatile("s_nop 7\n\ts_nop 7" ::: "memory");
    // stage to LDS PERMUTED (row = local site, col = permuted channel)
    unsigned short* ss = &stg[wave][0];
    const int pbase = ((n >> 2) * 16) + (n & 3);   // + (ct&3)*64 + (ct>>2)*4
#pragma unroll
    for (int ct = 0; ct < 16; ++ct) {
        const int cidx = pbase + (ct & 3) * 64 + (ct >> 2) * 4;
#pragma unroll
        for (int reg = 0; reg < 4; ++reg)
            ss[(q * 4 + reg) * SP_PAD + cidx] = f2bf(acc[ct][reg]);
    }
    __builtin_amdgcn_s_waitcnt(0);   // drain lgkm before wave-local readback
#pragma unroll
    for (int i = 0; i < 8; ++i) {
        int g = i * 64 + lane;
        int r = g >> 5, c = g & 31;
        if (sbase + r < NS_) {
            u32x4_t v = *(const u32x4_t*)(ss + r * SP_PAD + c * 8);
            *(u32x4_t*)(xs + (size_t)(sbase + r) * 256 + c * 8) = v;
        }
    }
}

// ---------------------------------------------------------------------------
// CSR build: histogram -> 3-phase scan -> scatter.
// Wells relation gets an inline descriptor desc[w]={start,deg,s0,s1} so the
// GAT kernel skips csr_src for deg<=2 (87% of wells).
// ---------------------------------------------------------------------------
__global__ void __launch_bounds__(256)
k_hist2(const int* __restrict__ d1, int* __restrict__ h1,
        const int* __restrict__ d2, int* __restrict__ h2)
{
    int e = blockIdx.x * 256 + threadIdx.x;
    if (e >= NE_) return;
    if (blockIdx.y == 0) atomicAdd(&h1[d1[e]], 1);
    else                 atomicAdd(&h2[d2[e]], 1);
}

__global__ void __launch_bounds__(256)
k_scan1_2(const int* __restrict__ h1, int n1, int* __restrict__ b1, int nb1,
          const int* __restrict__ h2, int n2, int* __restrict__ b2)
{
    __shared__ int red[256];
    const int tid = threadIdx.x;
    const int bx = blockIdx.x;
    const int* hist; int n; int* bsum; int blk;
    if (bx < nb1) { hist = h1; n = n1; bsum = b1; blk = bx; }
    else          { hist = h2; n = n2; bsum = b2; blk = bx - nb1; }
    int base = blk * EPB + tid * 8;
    int s = 0;
#pragma unroll
    for (int i = 0; i < 8; ++i) { int idx = base + i; if (idx < n) s += hist[idx]; }
    red[tid] = s;
    __syncthreads();
    for (int off = 128; off > 0; off >>= 1) {
        if (tid < off) red[tid] += red[tid + off];
        __syncthreads();
    }
    if (tid == 0) bsum[blk] = red[0];
}

__global__ void __launch_bounds__(256)
k_scan2_2(int* __restrict__ b1, int nb1, int* __restrict__ b2, int nb2)
{
    __shared__ int sh[256];
    const int tid = threadIdx.x;
    int* bsum = blockIdx.x == 0 ? b1 : b2;
    int nb = blockIdx.x == 0 ? nb1 : nb2;
    sh[tid] = (tid < nb) ? bsum[tid] : 0;
    __syncthreads();
    for (int off = 1; off < 256; off <<= 1) {
        int u = (tid >= off) ? sh[tid - off] : 0;
        __syncthreads();
        sh[tid] += u;
        __syncthreads();
    }
    if (tid < nb) bsum[tid] = (tid == 0) ? 0 : sh[tid - 1];
}

// rel-1 (wells): writes desc[w] = {start, deg, 0, 0}
// rel-2 (sites): writes rowptr + cursor as before
__global__ void __launch_bounds__(256)
k_scan3_2(const int* __restrict__ h1, int n1, const int* __restrict__ b1,
          int4* __restrict__ desc, int nb1,
          const int* __restrict__ h2, int n2, const int* __restrict__ b2,
          int* __restrict__ rp2, int* __restrict__ cu2)
{
    __shared__ int tsum[256];
    const int tid = threadIdx.x;
    const int bx = blockIdx.x;
    const int* hist; int n; const int* bsum; int blk; int wells;
    if (bx < nb1) { hist = h1; n = n1; bsum = b1; blk = bx; wells = 1; }
    else          { hist = h2; n = n2; bsum = b2; blk = bx - nb1; wells = 0; }
    int base = blk * EPB + tid * 8;
    int v[8]; int s = 0;
#pragma unroll
    for (int i = 0; i < 8; ++i) {
        int idx = base + i;
        v[i] = (idx < n) ? hist[idx] : 0;
        s += v[i];
    }
    tsum[tid] = s;
    __syncthreads();
    for (int off = 1; off < 256; off <<= 1) {
        int u = (tid >= off) ? tsum[tid - off] : 0;
        __syncthreads();
        tsum[tid] += u;
        __syncthreads();
    }
    int texcl = tsum[tid] - s;
    int run = bsum[blk] + texcl;
    if (wells) {
#pragma unroll
        for (int i = 0; i < 8; ++i) {
            int idx = base + i;
            if (idx < n) { desc[idx] = make_int4(run, v[i], 0, 0); run += v[i]; }
        }
    } else {
#pragma unroll
        for (int i = 0; i < 8; ++i) {
            int idx = base + i;
            if (idx < n) { rp2[idx] = run; cu2[idx] = run; run += v[i]; }
        }
        if (blk == 0 && tid == 0) rp2[n] = NE_;
    }
}

__global__ void __launch_bounds__(256)
k_scatter2(const int* __restrict__ s1, const int* __restrict__ d1,
           int* __restrict__ cnt0, int* __restrict__ desc_i, int* __restrict__ o1,
           const int* __restrict__ s2, const int* __restrict__ d2,
           int* __restrict__ c2, int* __restrict__ o2)
{
    int e = blockIdx.x * 256 + threadIdx.x;
    if (e >= NE_) return;
    if (blockIdx.y == 0) {
        int d = d1[e], s = s1[e];
        int pr = atomicAdd(&cnt0[d], 1);
        int start = desc_i[4 * d];
        o1[start + pr] = s;
        if (pr < 2) desc_i[4 * d + 2 + pr] = s;   // unique slot -> no race
    } else {
        int p = atomicAdd(&c2[d2[e]], 1);
        o2[p] = s2[e];
    }
}

// ---------------------------------------------------------------------------
// FUSED wells path: GAT gather (desc inline-CSR + permuted xs, prefetch
// ladder) + wells dense (MFMA) + output head. 16 wells/block.
// ---------------------------------------------------------------------------
__global__ void __launch_bounds__(256)
k_gat_wells(const float* __restrict__ x_wells, const float* __restrict__ vd,
            const int4* __restrict__ desc, const int* __restrict__ csr_src,
            const float* __restrict__ al_s, const unsigned short* __restrict__ xs,
            const float* __restrict__ b_sw, const float* __restrict__ bl_ww,
            const u32x4_t* __restrict__ fw, const float* __restrict__ Wg,
            const float* __restrict__ bg, float* __restrict__ out)
{
    __shared__ float vdl[16][17];     // pad 17: conflict-free vdl[p][j] reads
    __shared__ unsigned xwB[16][36];  // x_wells rows, bf16 pairs (K=64)
    __shared__ float dl[16][68];      // dense MFMA result, [well][channel]
    __shared__ float biasl[64];
    __shared__ float wgl[64];
    __shared__ float res[16];
    const int tid = threadIdx.x;
    vdl[tid >> 4][tid & 15] = vd[tid];
    if (tid < 64) { biasl[tid] = b_sw[tid] + bl_ww[tid]; wgl[tid] = Wg[tid]; }
    __syncthreads();
    const int wl = tid >> 4, p = tid & 15;
    const int w = blockIdx.x * 16 + wl;
    // descriptor: {start, deg, s0, s1}; s0/s1 = 0 when unwritten (safe loads)
    const int4 dsc = desc[w];
    const int deg = dsc.y;
    // ---- prefetch first two edges (covers 87% of wells fully) ----
    float4 as0 = ((const float4*)al_s)[dsc.z];
    const unsigned short* x0p = xs + (size_t)dsc.z * 256 + p * 16;
    u32x4_t va0 = *(const u32x4_t*)(x0p);
    u32x4_t vb0 = *(const u32x4_t*)(x0p + 8);
    float4 as1 = as0; u32x4_t va1 = va0, vb1 = vb0;
    if (deg > 1) {
        as1 = ((const float4*)al_s)[dsc.w];
        const unsigned short* x1p = xs + (size_t)dsc.w * 256 + p * 16;
        va1 = *(const u32x4_t*)(x1p);
        vb1 = *(const u32x4_t*)(x1p + 8);
    }
    // ---- h = x_w . vd (per head), overlaps the prefetch latency ----
    float h0, h1, h2, h3;
    {
        float4 xv = *(const float4*)(x_wells + (size_t)w * 64 + 4 * p);
        xwB[wl][2 * p]     = pk(xv.x, xv.y);
        xwB[wl][2 * p + 1] = pk(xv.z, xv.w);
        const float* vp = vdl[p];
        h0 = xv.x * vp[0] + xv.y * vp[4] + xv.z * vp[8]  + xv.w * vp[12];
        h1 = xv.x * vp[1] + xv.y * vp[5] + xv.z * vp[9]  + xv.w * vp[13];
        h2 = xv.x * vp[2] + xv.y * vp[6] + xv.z * vp[10] + xv.w * vp[14];
        h3 = xv.x * vp[3] + xv.y * vp[7] + xv.z * vp[11] + xv.w * vp[15];
    }
#pragma unroll
    for (int off = 1; off < 16; off <<= 1) {
        h0 += __shfl_xor(h0, off, 64);
        h1 += __shfl_xor(h1, off, 64);
        h2 += __shfl_xor(h2, off, 64);
        h3 += __shfl_xor(h3, off, 64);
    }
    float den0 = 0, den1 = 0, den2 = 0, den3 = 0;
    float n0[4] = {0, 0, 0, 0}, n1[4] = {0, 0, 0, 0};
    float n2[4] = {0, 0, 0, 0}, n3[4] = {0, 0, 0, 0};
    auto acc_edge = [&](float4 as, u32x4_t va, u32x4_t vb) {
        float e0 = __expf(lrelu02(as.x + h0));
        float e1 = __expf(lrelu02(as.y + h1));
        float e2 = __expf(lrelu02(as.z + h2));
        float e3 = __expf(lrelu02(as.w + h3));
        den0 += e0; den1 += e1; den2 += e2; den3 += e3;
        n0[0] += e0 * lo16(va[0]); n0[1] += e0 * hi16(va[0]);
        n0[2] += e0 * lo16(va[1]); n0[3] += e0 * hi16(va[1]);
        n1[0] += e1 * lo16(va[2]); n1[1] += e1 * hi16(va[2]);
        n1[2] += e1 * lo16(va[3]); n1[3] += e1 * hi16(va[3]);
        n2[0] += e2 * lo16(vb[0]); n2[1] += e2 * hi16(vb[0]);
        n2[2] += e2 * lo16(vb[1]); n2[3] += e2 * hi16(vb[1]);
        n3[0] += e3 * lo16(vb[2]); n3[1] += e3 * hi16(vb[2]);
        n3[2] += e3 * lo16(vb[3]); n3[3] += e3 * hi16(vb[3]);
    };
    if (deg > 0) acc_edge(as0, va0, vb0);
    if (deg > 1) acc_edge(as1, va1, vb1);
    for (int j = 2; j < deg; ++j) {
        int s = csr_src[dsc.x + j];
        float4 as = ((const float4*)al_s)[s];
        const unsigned short* xr = xs + (size_t)s * 256 + p * 16;
        u32x4_t va = *(const u32x4_t*)(xr);
        u32x4_t vb = *(const u32x4_t*)(xr + 8);
        acc_edge(as, va, vb);
    }
    const int c0 = 4 * p;
    float tmsg[4];
    if (deg > 0) {
        float i0 = 0.25f / den0, i1 = 0.25f / den1, i2 = 0.25f / den2, i3 = 0.25f / den3;
#pragma unroll
        for (int i = 0; i < 4; ++i)
            tmsg[i] = n0[i] * i0 + n1[i] * i1 + n2[i] * i2 + n3[i] * i3 + biasl[c0 + i];
    } else {
#pragma unroll
        for (int i = 0; i < 4; ++i) tmsg[i] = biasl[c0 + i];
    }
    __syncthreads();   // xwB fully staged
    // ---- dense phase: wave = col-tile ct; A rows = block's 16 wells ----
    const int wave = __builtin_amdgcn_readfirstlane(tid >> 6);
    const int lane = tid & 63, q = lane >> 4, n = lane & 15;
    u32x4_t ax0 = *(const u32x4_t*)&xwB[n][q * 4];
    u32x4_t ax1 = *(const u32x4_t*)&xwB[n][16 + q * 4];
    f32x4_t acc = {0, 0, 0, 0};
    asm volatile("s_nop 3" : "+v"(ax0), "+v"(ax1), "+v"(acc));
    mfma_bf16(acc, ax0, fw[wave * 64 + lane]);
    mfma_bf16(acc, ax1, fw[(4 + wave) * 64 + lane]);
    asm volatile("s_nop 7\n\ts_nop 7" : "+v"(acc));
#pragma unroll
    for (int reg = 0; reg < 4; ++reg)
        dl[q * 4 + reg][wave * 16 + n] = acc[reg];   // row=well, col=channel
    __syncthreads();
    float4 dv = *(const float4*)&dl[wl][c0];
    float t0 = tmsg[0] + dv.x;
    float t1 = tmsg[1] + dv.y;
    float t2 = tmsg[2] + dv.z;
    float t3 = tmsg[3] + dv.w;
    float pr = fmaxf(t0, 0.f) * wgl[c0] + fmaxf(t1, 0.f) * wgl[c0 + 1] +
               fmaxf(t2, 0.f) * wgl[c0 + 2] + fmaxf(t3, 0.f) * wgl[c0 + 3];
    pr += __shfl_xor(pr, 1, 64);
    pr += __shfl_xor(pr, 2, 64);
    pr += __shfl_xor(pr, 4, 64);
    pr += __shfl_xor(pr, 8, 64);
    if (p == 0) res[wl] = pr + bg[0];
    __syncthreads();
    if (tid < 16) {
        float v = res[tid];
        out[blockIdx.x * 16 + tid] = v > 0.f ? v : 0.01f * v;
    }
}

// ---------------------------------------------------------------------------
// FUSED sites path: SAGE gather (f32 mean) + sites dense (K=128 MFMA) + head.
// A-operands staged as packed bf16 pairs (pitch 36 -> conflict-free b128).
// ---------------------------------------------------------------------------
__global__ void __launch_bounds__(256)
k_sage_sites(const float* __restrict__ x_sites, const float* __restrict__ x_wells,
             const int* __restrict__ rowptr, const int* __restrict__ csr_src,
             const u32x4_t* __restrict__ fs, const float* __restrict__ bl_ws,
             const float* __restrict__ b_ss, const float* __restrict__ Wsit,
             const float* __restrict__ bsit, float* __restrict__ out)
{
    __shared__ unsigned mnB[16][36];
    __shared__ unsigned xB[16][36];
    __shared__ float dl[16][68];
    __shared__ float biasl[64];
    __shared__ float wsl[64];
    __shared__ float res[16];
    const int tid = threadIdx.x;
    if (tid < 64) { biasl[tid] = bl_ws[tid] + b_ss[tid]; wsl[tid] = Wsit[tid]; }
    const int sl = tid >> 4, p = tid & 15;
    const int s = blockIdx.x * 16 + sl;
    const int r0 = rowptr[s], r1 = rowptr[s + 1];
    float4 m4 = {0.f, 0.f, 0.f, 0.f};
    for (int j = r0; j < r1; ++j) {
        int wsrc = csr_src[j];
        float4 xv = ((const float4*)(x_wells + (size_t)wsrc * 64))[p];
        m4.x += xv.x; m4.y += xv.y; m4.z += xv.z; m4.w += xv.w;
    }
    if (r1 > r0) {
        float rc = 1.f / (float)(r1 - r0);
        m4.x *= rc; m4.y *= rc; m4.z *= rc; m4.w *= rc;
    }
    mnB[sl][2 * p]     = pk(m4.x, m4.y);
    mnB[sl][2 * p + 1] = pk(m4.z, m4.w);
    {
        float4 xv = *(const float4*)(x_sites + (size_t)s * 64 + 4 * p);
        xB[sl][2 * p]     = pk(xv.x, xv.y);
        xB[sl][2 * p + 1] = pk(xv.z, xv.w);
    }
    __syncthreads();
    // ---- dense phase: wave = col-tile ct; A rows = block's 16 sites ----
    const int wave = __builtin_amdgcn_readfirstlane(tid >> 6);
    const int lane = tid & 63, q = lane >> 4, n = lane & 15;
    u32x4_t am0 = *(const u32x4_t*)&mnB[n][q * 4];
    u32x4_t am1 = *(const u32x4_t*)&mnB[n][16 + q * 4];
    u32x4_t ax0 = *(const u32x4_t*)&xB[n][q * 4];
    u32x4_t ax1 = *(const u32x4_t*)&xB[n][16 + q * 4];
    f32x4_t acc = {0, 0, 0, 0};
    asm volatile("s_nop 3" : "+v"(am0), "+v"(am1), "+v"(ax0), "+v"(ax1), "+v"(acc));
    mfma_bf16(acc, am0, fs[wave * 64 + lane]);
    mfma_bf16(acc, am1, fs[(4 + wave) * 64 + lane]);
    mfma_bf16(acc, ax0, fs[(8 + wave) * 64 + lane]);
    mfma_bf16(acc, ax1, fs[(12 + wave) * 64 + lane]);
    asm volatile("s_nop 7\n\ts_nop 7" : "+v"(acc));
#pragma unroll
    for (int reg = 0; reg < 4; ++reg)
        dl[q * 4 + reg][wave * 16 + n] = acc[reg];   // row=site, col=channel
    __syncthreads();
    const int c0 = 4 * p;
    float4 dv = *(const float4*)&dl[sl][c0];
    float t0 = dv.x + biasl[c0];
    float t1 = dv.y + biasl[c0 + 1];
    float t2 = dv.z + biasl[c0 + 2];
    float t3 = dv.w + biasl[c0 + 3];
    float pr = fmaxf(t0, 0.f) * wsl[c0] + fmaxf(t1, 0.f) * wsl[c0 + 1] +
               fmaxf(t2, 0.f) * wsl[c0 + 2] + fmaxf(t3, 0.f) * wsl[c0 + 3];
    pr += __shfl_xor(pr, 1, 64);
    pr += __shfl_xor(pr, 2, 64);
    pr += __shfl_xor(pr, 4, 64);
    pr += __shfl_xor(pr, 8, 64);
    if (p == 0) res[sl] = pr + bsit[0];
    __syncthreads();
    if (tid < 16) {
        float v = res[tid];
        out[(size_t)NW_ + blockIdx.x * 16 + tid] = v > 0.f ? v : 0.01f * v;
    }
}

// ---------------------------------------------------------------------------
extern "C" void kernel_launch(void* const* d_in, const int* in_sizes, int n_in,
                              void* d_out, int out_size, void* d_ws, size_t ws_size,
                              hipStream_t stream)
{
    const float* x_sites    = (const float*)d_in[0];
    const float* x_wells    = (const float*)d_in[1];
    const int*   e_sw_src   = (const int*)d_in[2];
    const int*   e_sw_dst   = (const int*)d_in[3];
    const int*   e_ws_src   = (const int*)d_in[4];
    const int*   e_ws_dst   = (const int*)d_in[5];
    const float* W_sw       = (const float*)d_in[6];
    const float* att_src_sw = (const float*)d_in[7];
    const float* att_dst_sw = (const float*)d_in[8];
    const float* b_sw       = (const float*)d_in[9];
    const float* Wl_ws      = (const float*)d_in[10];
    const float* bl_ws      = (const float*)d_in[11];
    const float* Wr_ws      = (const float*)d_in[12];
    const float* W_ss       = (const float*)d_in[13];
    // d_in[14], d_in[15]: att_*_ss cancel (softmax over single self edge == 1)
    const float* b_ss       = (const float*)d_in[16];
    const float* Wl_ww      = (const float*)d_in[17];
    const float* bl_ww      = (const float*)d_in[18];
    const float* Wr_ww      = (const float*)d_in[19];
    const float* Wg         = (const float*)d_in[20];
    const float* bg         = (const float*)d_in[21];
    const float* Wsit       = (const float*)d_in[22];
    const float* bsit       = (const float*)d_in[23];
    float* out = (float*)d_out;

    // workspace layout
    unsigned short* xs = (unsigned short*)d_ws;            // NS*256 bf16 (permuted)
    float* al_s = (float*)(xs + (size_t)NS_ * 256);        // NS*4
    float* vd   = al_s + (size_t)NS_ * 4;                  // 256
    float* vs   = vd + 256;                                // 256
    u32x4_t* fw = (u32x4_t*)(vs + 256);                    // 512  (8 KB)
    u32x4_t* fs = fw + 512;                                // 1024 (16 KB)
    u32x4_t* fsp= fs + 1024;                               // 2048 (32 KB)
    int* ip     = (int*)(fsp + 2048);
    int* h_sw   = ip;                                      // NW   (zeroed)
    int* h_ws   = h_sw + NW_;                              // NS   (zeroed)
    int* cnt0   = h_ws + NS_;                              // NW   (zeroed, adjacent)
    int* desc_i = cnt0 + NW_;                              // 4*NW (int4 aligned)
    int* csr_sw = desc_i + 4 * (size_t)NW_;                // E
    int* bs_sw  = csr_sw + NE_;                            // 256
    int* rp_ws  = bs_sw + 256;                             // NS+4
    int* cur_ws = rp_ws + NS_ + 4;                         // NS
    int* csr_ws = cur_ws + NS_;                            // E
    int* bs_ws  = csr_ws + NE_;                            // 256

    hipMemsetAsync(h_sw, 0, (size_t)(NW_ + NS_ + NW_) * sizeof(int), stream);

    const int egrid = (NE_ + 255) / 256;
    const int nb_sw = (NW_ + EPB - 1) / EPB;   // 196
    const int nb_ws = (NS_ + EPB - 1) / EPB;   // 49

    hipLaunchKernelGGL(k_hist2, dim3(egrid, 2), dim3(256), 0, stream,
                       e_sw_dst, h_sw, e_ws_dst, h_ws);
    hipLaunchKernelGGL(k_scan1_2, dim3(nb_sw + nb_ws), dim3(256), 0, stream,
                       h_sw, NW_, bs_sw, nb_sw, h_ws, NS_, bs_ws);
    hipLaunchKernelGGL(k_scan2_2, dim3(2), dim3(256), 0, stream,
                       bs_sw, nb_sw, bs_ws, nb_ws);
    hipLaunchKernelGGL(k_scan3_2, dim3(nb_sw + nb_ws), dim3(256), 0, stream,
                       h_sw, NW_, bs_sw, (int4*)desc_i, nb_sw,
                       h_ws, NS_, bs_ws, rp_ws, cur_ws);
    hipLaunchKernelGGL(k_scatter2, dim3(egrid, 2), dim3(256), 0, stream,
                       e_sw_src, e_sw_dst, cnt0, desc_i, csr_sw,
                       e_ws_src, e_ws_dst, cur_ws, csr_ws);

    hipLaunchKernelGGL(k_prep, dim3(1), dim3(256), 0, stream,
                       W_sw, att_src_sw, att_dst_sw, Wl_ww, Wr_ww, Wl_ws, Wr_ws, W_ss,
                       vd, vs, fw, fs, fsp);
    hipLaunchKernelGGL(k_sites_pre, dim3((NS_ + 63) / 64), dim3(256), 0, stream,
                       x_sites, fsp, vs, xs, al_s);

    hipLaunchKernelGGL(k_gat_wells, dim3(NW_ / 16), dim3(256), 0, stream,
                       x_wells, vd, (const int4*)desc_i, csr_sw, al_s, xs,
                       b_sw, bl_ww, fw, Wg, bg, out);
    hipLaunchKernelGGL(k_sage_sites, dim3(NS_ / 16), dim3(256), 0, stream,
                       x_sites, x_wells, rp_ws, csr_ws, fs, bl_ws, b_ss,
                       Wsit, bsit, out);
}

// Round 5
// 470.788 us; speedup vs baseline: 1.0233x; 1.0172x over previous
//
#include <hip/hip_runtime.h>

#define NS_ 100000
#define NW_ 400000
#define NE_ 500000
#define EPB 2048   // elements per scan block

#define SAGE_BLKS (NS_ / 16)              // 6250
#define GAT_BLKS  (NW_ / 16)              // 25000

typedef float f32x4_t __attribute__((ext_vector_type(4)));
typedef unsigned u32x4_t __attribute__((ext_vector_type(4)));

__device__ __forceinline__ float lrelu02(float x) { return x > 0.f ? x : 0.2f * x; }
__device__ __forceinline__ float bf2f(unsigned short u) {
    return __uint_as_float(((unsigned)u) << 16);
}
__device__ __forceinline__ float lo16(unsigned u) { return __uint_as_float(u << 16); }
__device__ __forceinline__ float hi16(unsigned u) { return __uint_as_float(u & 0xFFFF0000u); }
__device__ __forceinline__ unsigned short f2bf(float f) {
    unsigned u = __float_as_uint(f);
    u += 0x7FFFu + ((u >> 16) & 1u);           // round-to-nearest-even
    return (unsigned short)(u >> 16);
}
__device__ __forceinline__ unsigned pk(float lo, float hi) {
    return (unsigned)f2bf(lo) | ((unsigned)f2bf(hi) << 16);
}
// D = A*B + D, 16x16x32 bf16. a/b = 8 bf16 packed in 4 dwords (k ascending).
// A[m=lane&15][k=(lane>>4)*8+j]; B[k=(lane>>4)*8+j][n=lane&15];
// D: col=lane&15, row=(lane>>4)*4+reg.   (layout HW-verified earlier)
__device__ __forceinline__ void mfma_bf16(f32x4_t& acc, u32x4_t a, u32x4_t b) {
    asm volatile("v_mfma_f32_16x16x32_bf16 %0, %1, %2, %0" : "+v"(acc) : "v"(a), "v"(b));
}

// ---------------------------------------------------------------------------
// Prep (15 blocks): vd/vs attention vectors + all weight B-fragments.
// bid 0    : vd/vs
// bid 1-2  : fw  (512 items)  Wc = Wl_ww + Wr_ww            (wells dense K=64)
// bid 3-6  : fs  (1024 items) Wl_ws | Wr_ws + mean W_ss     (sites dense K=128)
// bid 7-14 : fsp (2048 items) W_sw [64,256] projection      (kc*16+ct)
// ---------------------------------------------------------------------------
__global__ void __launch_bounds__(256)
k_prep(const float* __restrict__ W_sw, const float* __restrict__ att_src,
       const float* __restrict__ att_dst,
       const float* __restrict__ Wl_ww, const float* __restrict__ Wr_ww,
       const float* __restrict__ Wl_ws, const float* __restrict__ Wr_ws,
       const float* __restrict__ W_ss,
       float* __restrict__ vd, float* __restrict__ vs,
       u32x4_t* __restrict__ fw, u32x4_t* __restrict__ fs,
       u32x4_t* __restrict__ fsp)
{
    const int tid = threadIdx.x;
    const int bid = blockIdx.x;
    if (bid == 0) {
        // vd (att_dst) and vs (att_src): v[d*4+h] = sum_c W_sw[d,h*64+c]*att[h,c]
        int d = tid >> 2, h = tid & 3;
        const float4* wp = (const float4*)(W_sw + d * 256 + h * 64);
        const float4* ad = (const float4*)(att_dst + h * 64);
        const float4* as = (const float4*)(att_src + h * 64);
        float accd = 0.f, accs = 0.f;
#pragma unroll
        for (int c = 0; c < 16; ++c) {
            float4 wv = wp[c]; float4 dv = ad[c]; float4 sv = as[c];
            accd += wv.x * dv.x + wv.y * dv.y + wv.z * dv.z + wv.w * dv.w;
            accs += wv.x * sv.x + wv.y * sv.y + wv.z * sv.z + wv.w * sv.w;
        }
        vd[d * 4 + h] = accd;
        vs[d * 4 + h] = accs;
    } else if (bid <= 2) {
        int idx = (bid - 1) * 256 + tid;           // [0,512)
        int f = idx >> 6, lane = idx & 63;
        int kc = f >> 2, ct = f & 3, q = lane >> 4, n = lane & 15;
        int c = ct * 16 + n;
        u32x4_t d;
#pragma unroll
        for (int i = 0; i < 4; ++i) {
            int k = kc * 32 + q * 8 + 2 * i;
            d[i] = pk(Wl_ww[k * 64 + c] + Wr_ww[k * 64 + c],
                      Wl_ww[(k + 1) * 64 + c] + Wr_ww[(k + 1) * 64 + c]);
        }
        fw[idx] = d;
    } else if (bid <= 6) {
        int idx = (bid - 3) * 256 + tid;           // [0,1024)
        int f = idx >> 6, lane = idx & 63;
        int kc = f >> 2, ct = f & 3, q = lane >> 4, n = lane & 15;
        int c = ct * 16 + n;
        u32x4_t d;
#pragma unroll
        for (int i = 0; i < 4; ++i) {
            int k = kc * 32 + q * 8 + 2 * i;
            float lo, hi;
            if (k < 64) {
                lo = Wl_ws[k * 64 + c];
                hi = Wl_ws[(k + 1) * 64 + c];
            } else {
                int kk = k - 64;
                lo = Wr_ws[kk * 64 + c] + 0.25f * (W_ss[kk * 256 + c] + W_ss[kk * 256 + 64 + c] +
                                                   W_ss[kk * 256 + 128 + c] + W_ss[kk * 256 + 192 + c]);
                hi = Wr_ws[(kk + 1) * 64 + c] + 0.25f * (W_ss[(kk + 1) * 256 + c] + W_ss[(kk + 1) * 256 + 64 + c] +
                                                         W_ss[(kk + 1) * 256 + 128 + c] + W_ss[(kk + 1) * 256 + 192 + c]);
            }
            d[i] = pk(lo, hi);
        }
        fs[idx] = d;
    } else {
        int idx = (bid - 7) * 256 + tid;           // [0,2048)
        int f = idx >> 6, lane = idx & 63;
        int kc = f >> 4, ct = f & 15, q = lane >> 4, n = lane & 15;
        int c = ct * 16 + n;
        u32x4_t d;
#pragma unroll
        for (int i = 0; i < 4; ++i) {
            int k = kc * 32 + q * 8 + 2 * i;
            d[i] = pk(W_sw[k * 256 + c], W_sw[(k + 1) * 256 + c]);
        }
        fsp[idx] = d;
    }
}

// ---------------------------------------------------------------------------
// Sites projection via MFMA: xs(bf16, PERMUTED [s][p][h*4+i]) = x_sites@W_sw,
// plus fused al_s = x_sites @ vs. Permutation: channel c=h*64+4p+i stored at
// ushort index p*16 + h*4 + i, so the gather reads 2x16B contiguous per lane.
// x_sites loads non-temporal (streamed once; keeps xs L3-resident later).
// ---------------------------------------------------------------------------
#define SP_PAD 264   // 256 + 8 ushorts row pad (bank rotation for b16 stores)
__global__ void __launch_bounds__(256)
k_sites_pre(const float* __restrict__ x_sites, const u32x4_t* __restrict__ fsp,
            const float* __restrict__ vs, unsigned short* __restrict__ xs,
            float* __restrict__ al_s)
{
    __shared__ unsigned short stg[4][16 * SP_PAD];
    __shared__ float vsl[256];
    const int tid = threadIdx.x;
    vsl[tid] = vs[tid];
    __syncthreads();
    const int wave = __builtin_amdgcn_readfirstlane(tid >> 6);
    const int lane = tid & 63, q = lane >> 4, n = lane & 15;
    const int sbase = blockIdx.x * 64 + wave * 16;
    const int srow = min(sbase + n, NS_ - 1);
    const float* xr = x_sites + (size_t)srow * 64 + q * 8;
    f32x4_t x0 = __builtin_nontemporal_load((const f32x4_t*)(xr));
    f32x4_t x1 = __builtin_nontemporal_load((const f32x4_t*)(xr + 4));
    f32x4_t x2 = __builtin_nontemporal_load((const f32x4_t*)(xr + 32));
    f32x4_t x3 = __builtin_nontemporal_load((const f32x4_t*)(xr + 36));
    u32x4_t am0 = { pk(x0[0], x0[1]), pk(x0[2], x0[3]), pk(x1[0], x1[1]), pk(x1[2], x1[3]) };
    u32x4_t am1 = { pk(x2[0], x2[1]), pk(x2[2], x2[3]), pk(x3[0], x3[1]), pk(x3[2], x3[3]) };
    // fused al_s partials over this lane's 16 k-values (fp32 x, exact path)
    float pa[4];
#pragma unroll
    for (int h = 0; h < 4; ++h) {
        const float* v0 = &vsl[(q * 8) * 4 + h];
        const float* v1 = &vsl[(32 + q * 8) * 4 + h];
        pa[h] = x0[0] * v0[0]  + x0[1] * v0[4]  + x0[2] * v0[8]  + x0[3] * v0[12]
              + x1[0] * v0[16] + x1[1] * v0[20] + x1[2] * v0[24] + x1[3] * v0[28]
              + x2[0] * v1[0]  + x2[1] * v1[4]  + x2[2] * v1[8]  + x2[3] * v1[12]
              + x3[0] * v1[16] + x3[1] * v1[20] + x3[2] * v1[24] + x3[3] * v1[28];
    }
#pragma unroll
    for (int h = 0; h < 4; ++h) {
        pa[h] += __shfl_xor(pa[h], 16, 64);
        pa[h] += __shfl_xor(pa[h], 32, 64);
    }
    if (q == 0 && sbase + n < NS_)
        *(float4*)(al_s + (size_t)(sbase + n) * 4) = make_float4(pa[0], pa[1], pa[2], pa[3]);

    f32x4_t acc[16];
#pragma unroll
    for (int ct = 0; ct < 16; ++ct) acc[ct] = (f32x4_t){0, 0, 0, 0};
    asm volatile("s_nop 3" : "+v"(am0), "+v"(am1));
#pragma unroll
    for (int ct = 0; ct < 16; ++ct) mfma_bf16(acc[ct], am0, fsp[ct * 64 + lane]);
#pragma unroll
    for (int ct = 0; ct < 16; ++ct) mfma_bf16(acc[ct], am1, fsp[(16 + ct) * 64 + lane]);
    asm volatile("s_nop 7\n\ts_nop 7" ::: "memory");
    // stage to LDS PERMUTED (row = local site, col = permuted channel)
    unsigned short* ss = &stg[wave][0];
    const int pbase = ((n >> 2) * 16) + (n & 3);   // + (ct&3)*64 + (ct>>2)*4
#pragma unroll
    for (int ct = 0; ct < 16; ++ct) {
        const int cidx = pbase + (ct & 3) * 64 + (ct >> 2) * 4;
#pragma unroll
        for (int reg = 0; reg < 4; ++reg)
            ss[(q * 4 + reg) * SP_PAD + cidx] = f2bf(acc[ct][reg]);
    }
    __builtin_amdgcn_s_waitcnt(0);   // drain lgkm before wave-local readback
#pragma unroll
    for (int i = 0; i < 8; ++i) {
        int g = i * 64 + lane;
        int r = g >> 5, c = g & 31;
        if (sbase + r < NS_) {
            u32x4_t v = *(const u32x4_t*)(ss + r * SP_PAD + c * 8);
            *(u32x4_t*)(xs + (size_t)(sbase + r) * 256 + c * 8) = v;
        }
    }
}

// ---------------------------------------------------------------------------
// CSR build: histogram -> 3-phase scan -> scatter (relations merged per launch)
// ---------------------------------------------------------------------------
__global__ void __launch_bounds__(256)
k_hist2(const int* __restrict__ d1, int* __restrict__ h1,
        const int* __restrict__ d2, int* __restrict__ h2)
{
    int e = blockIdx.x * 256 + threadIdx.x;
    if (e >= NE_) return;
    if (blockIdx.y == 0) atomicAdd(&h1[d1[e]], 1);
    else                 atomicAdd(&h2[d2[e]], 1);
}

__global__ void __launch_bounds__(256)
k_scan1_2(const int* __restrict__ h1, int n1, int* __restrict__ b1, int nb1,
          const int* __restrict__ h2, int n2, int* __restrict__ b2)
{
    __shared__ int red[256];
    const int tid = threadIdx.x;
    const int bx = blockIdx.x;
    const int* hist; int n; int* bsum; int blk;
    if (bx < nb1) { hist = h1; n = n1; bsum = b1; blk = bx; }
    else          { hist = h2; n = n2; bsum = b2; blk = bx - nb1; }
    int base = blk * EPB + tid * 8;
    int s = 0;
#pragma unroll
    for (int i = 0; i < 8; ++i) { int idx = base + i; if (idx < n) s += hist[idx]; }
    red[tid] = s;
    __syncthreads();
    for (int off = 128; off > 0; off >>= 1) {
        if (tid < off) red[tid] += red[tid + off];
        __syncthreads();
    }
    if (tid == 0) bsum[blk] = red[0];
}

__global__ void __launch_bounds__(256)
k_scan2_2(int* __restrict__ b1, int nb1, int* __restrict__ b2, int nb2)
{
    __shared__ int sh[256];
    const int tid = threadIdx.x;
    int* bsum = blockIdx.x == 0 ? b1 : b2;
    int nb = blockIdx.x == 0 ? nb1 : nb2;
    sh[tid] = (tid < nb) ? bsum[tid] : 0;
    __syncthreads();
    for (int off = 1; off < 256; off <<= 1) {
        int u = (tid >= off) ? sh[tid - off] : 0;
        __syncthreads();
        sh[tid] += u;
        __syncthreads();
    }
    if (tid < nb) bsum[tid] = (tid == 0) ? 0 : sh[tid - 1];
}

__global__ void __launch_bounds__(256)
k_scan3_2(const int* __restrict__ h1, int n1, const int* __restrict__ b1,
          int* __restrict__ rp1, int* __restrict__ cu1, int nb1,
          const int* __restrict__ h2, int n2, const int* __restrict__ b2,
          int* __restrict__ rp2, int* __restrict__ cu2)
{
    __shared__ int tsum[256];
    const int tid = threadIdx.x;
    const int bx = blockIdx.x;
    const int* hist; int n; const int* bsum; int* rowptr; int* cursor; int blk;
    if (bx < nb1) { hist = h1; n = n1; bsum = b1; rowptr = rp1; cursor = cu1; blk = bx; }
    else          { hist = h2; n = n2; bsum = b2; rowptr = rp2; cursor = cu2; blk = bx - nb1; }
    int base = blk * EPB + tid * 8;
    int v[8]; int s = 0;
#pragma unroll
    for (int i = 0; i < 8; ++i) {
        int idx = base + i;
        v[i] = (idx < n) ? hist[idx] : 0;
        s += v[i];
    }
    tsum[tid] = s;
    __syncthreads();
    for (int off = 1; off < 256; off <<= 1) {
        int u = (tid >= off) ? tsum[tid - off] : 0;
        __syncthreads();
        tsum[tid] += u;
        __syncthreads();
    }
    int texcl = tsum[tid] - s;
    int run = bsum[blk] + texcl;
#pragma unroll
    for (int i = 0; i < 8; ++i) {
        int idx = base + i;
        if (idx < n) { rowptr[idx] = run; cursor[idx] = run; run += v[i]; }
    }
    if (blk == 0 && tid == 0) rowptr[n] = NE_;
}

__global__ void __launch_bounds__(256)
k_scatter2(const int* __restrict__ s1, const int* __restrict__ d1,
           int* __restrict__ c1, int* __restrict__ o1,
           const int* __restrict__ s2, const int* __restrict__ d2,
           int* __restrict__ c2, int* __restrict__ o2)
{
    int e = blockIdx.x * 256 + threadIdx.x;
    if (e >= NE_) return;
    if (blockIdx.y == 0) { int p = atomicAdd(&c1[d1[e]], 1); o1[p] = s1[e]; }
    else                 { int p = atomicAdd(&c2[d2[e]], 1); o2[p] = s2[e]; }
}

// ---------------------------------------------------------------------------
// FINAL merged launch: sage-sites (bid%5==0) UNION gat-wells (else),
// INTERLEAVED so both block types co-reside the whole launch (round-3's
// sequential ordering gave no overlap). 31250 = 5 x 6250 exactly.
// gat body: round-1 loop (no prefetch ladder, low VGPR) + permuted 16B xs
// loads + non-temporal x_wells stream (protects xs L3 residency).
// ---------------------------------------------------------------------------
__global__ void __launch_bounds__(256)
k_fin(const float* __restrict__ x_sites, const float* __restrict__ x_wells,
      const int* __restrict__ rp_ws, const int* __restrict__ csr_ws,
      const u32x4_t* __restrict__ fs, const float* __restrict__ bl_ws,
      const float* __restrict__ b_ss, const float* __restrict__ Wsit,
      const float* __restrict__ bsit,
      const float* __restrict__ vd, const int* __restrict__ rp_sw,
      const int* __restrict__ csr_sw, const float* __restrict__ al_s,
      const unsigned short* __restrict__ xs, const float* __restrict__ b_sw,
      const float* __restrict__ bl_ww, const u32x4_t* __restrict__ fw,
      const float* __restrict__ Wg, const float* __restrict__ bg,
      float* __restrict__ out)
{
    __shared__ float smem[2384];
    const int tid = threadIdx.x;
    const int bid = blockIdx.x;

    if (bid % 5 == 0) {
        // ================= SAGE sites body =================
        const int sb = bid / 5;
        unsigned* mnB = (unsigned*)smem;           // [16][36]
        unsigned* xB  = (unsigned*)(smem + 576);   // [16][36]
        float* dl     = smem + 1152;               // [16][68]
        float* biasl  = smem + 2240;               // [64]
        float* wsl    = smem + 2304;               // [64]
        float* res    = smem + 2368;               // [16]
        if (tid < 64) { biasl[tid] = bl_ws[tid] + b_ss[tid]; wsl[tid] = Wsit[tid]; }
        const int sl = tid >> 4, p = tid & 15;
        const int s = sb * 16 + sl;
        const int r0 = rp_ws[s], r1 = rp_ws[s + 1];
        float4 m4 = {0.f, 0.f, 0.f, 0.f};
        for (int j = r0; j < r1; ++j) {
            int wsrc = csr_ws[j];
            float4 xv = ((const float4*)(x_wells + (size_t)wsrc * 64))[p];
            m4.x += xv.x; m4.y += xv.y; m4.z += xv.z; m4.w += xv.w;
        }
        if (r1 > r0) {
            float rc = 1.f / (float)(r1 - r0);
            m4.x *= rc; m4.y *= rc; m4.z *= rc; m4.w *= rc;
        }
        mnB[sl * 36 + 2 * p]     = pk(m4.x, m4.y);
        mnB[sl * 36 + 2 * p + 1] = pk(m4.z, m4.w);
        {
            f32x4_t xv = __builtin_nontemporal_load(
                (const f32x4_t*)(x_sites + (size_t)s * 64 + 4 * p));
            xB[sl * 36 + 2 * p]     = pk(xv[0], xv[1]);
            xB[sl * 36 + 2 * p + 1] = pk(xv[2], xv[3]);
        }
        __syncthreads();
        const int wave = __builtin_amdgcn_readfirstlane(tid >> 6);
        const int lane = tid & 63, q = lane >> 4, n = lane & 15;
        u32x4_t am0 = *(const u32x4_t*)&mnB[n * 36 + q * 4];
        u32x4_t am1 = *(const u32x4_t*)&mnB[n * 36 + 16 + q * 4];
        u32x4_t ax0 = *(const u32x4_t*)&xB[n * 36 + q * 4];
        u32x4_t ax1 = *(const u32x4_t*)&xB[n * 36 + 16 + q * 4];
        f32x4_t acc = {0, 0, 0, 0};
        asm volatile("s_nop 3" : "+v"(am0), "+v"(am1), "+v"(ax0), "+v"(ax1), "+v"(acc));
        mfma_bf16(acc, am0, fs[wave * 64 + lane]);
        mfma_bf16(acc, am1, fs[(4 + wave) * 64 + lane]);
        mfma_bf16(acc, ax0, fs[(8 + wave) * 64 + lane]);
        mfma_bf16(acc, ax1, fs[(12 + wave) * 64 + lane]);
        asm volatile("s_nop 7\n\ts_nop 7" : "+v"(acc));
#pragma unroll
        for (int reg = 0; reg < 4; ++reg)
            dl[(q * 4 + reg) * 68 + wave * 16 + n] = acc[reg];
        __syncthreads();
        const int c0 = 4 * p;
        float4 dv = *(const float4*)&dl[sl * 68 + c0];
        float t0 = dv.x + biasl[c0];
        float t1 = dv.y + biasl[c0 + 1];
        float t2 = dv.z + biasl[c0 + 2];
        float t3 = dv.w + biasl[c0 + 3];
        float pr = fmaxf(t0, 0.f) * wsl[c0] + fmaxf(t1, 0.f) * wsl[c0 + 1] +
                   fmaxf(t2, 0.f) * wsl[c0 + 2] + fmaxf(t3, 0.f) * wsl[c0 + 3];
        pr += __shfl_xor(pr, 1, 64);
        pr += __shfl_xor(pr, 2, 64);
        pr += __shfl_xor(pr, 4, 64);
        pr += __shfl_xor(pr, 8, 64);
        if (p == 0) res[sl] = pr + bsit[0];
        __syncthreads();
        if (tid < 16) {
            float v = res[tid];
            out[(size_t)NW_ + sb * 16 + tid] = v > 0.f ? v : 0.01f * v;
        }
        return;
    }

    // ================= GAT wells body =================
    {
        const int gb = bid - 1 - bid / 5;
        float* vdl    = smem;                       // [16][17]
        unsigned* xwB = (unsigned*)(smem + 272);    // [16][36]
        float* dl     = smem + 848;                 // [16][68]
        float* biasl  = smem + 1936;                // [64]
        float* wgl    = smem + 2000;                // [64]
        float* res    = smem + 2064;                // [16]
        vdl[(tid >> 4) * 17 + (tid & 15)] = vd[tid];
        if (tid < 64) { biasl[tid] = b_sw[tid] + bl_ww[tid]; wgl[tid] = Wg[tid]; }
        __syncthreads();
        const int wl = tid >> 4, p = tid & 15;
        const int w = gb * 16 + wl;
        const int r0 = rp_sw[w], r1 = rp_sw[w + 1];
        float h0, h1, h2, h3;
        {
            f32x4_t xv = __builtin_nontemporal_load(
                (const f32x4_t*)(x_wells + (size_t)w * 64 + 4 * p));
            xwB[wl * 36 + 2 * p]     = pk(xv[0], xv[1]);
            xwB[wl * 36 + 2 * p + 1] = pk(xv[2], xv[3]);
            const float* vp = &vdl[p * 17];
            h0 = xv[0] * vp[0] + xv[1] * vp[4] + xv[2] * vp[8]  + xv[3] * vp[12];
            h1 = xv[0] * vp[1] + xv[1] * vp[5] + xv[2] * vp[9]  + xv[3] * vp[13];
            h2 = xv[0] * vp[2] + xv[1] * vp[6] + xv[2] * vp[10] + xv[3] * vp[14];
            h3 = xv[0] * vp[3] + xv[1] * vp[7] + xv[2] * vp[11] + xv[3] * vp[15];
        }
#pragma unroll
        for (int off = 1; off < 16; off <<= 1) {
            h0 += __shfl_xor(h0, off, 64);
            h1 += __shfl_xor(h1, off, 64);
            h2 += __shfl_xor(h2, off, 64);
            h3 += __shfl_xor(h3, off, 64);
        }
        float den0 = 0, den1 = 0, den2 = 0, den3 = 0;
        float n0[4] = {0, 0, 0, 0}, n1[4] = {0, 0, 0, 0};
        float n2[4] = {0, 0, 0, 0}, n3[4] = {0, 0, 0, 0};
        for (int j = r0; j < r1; ++j) {
            int s = csr_sw[j];
            float4 as = ((const float4*)al_s)[s];
            const unsigned short* xr = xs + (size_t)s * 256 + p * 16;
            u32x4_t va = *(const u32x4_t*)(xr);
            u32x4_t vb = *(const u32x4_t*)(xr + 8);
            float e0 = __expf(lrelu02(as.x + h0));
            float e1 = __expf(lrelu02(as.y + h1));
            float e2 = __expf(lrelu02(as.z + h2));
            float e3 = __expf(lrelu02(as.w + h3));
            den0 += e0; den1 += e1; den2 += e2; den3 += e3;
            n0[0] += e0 * lo16(va[0]); n0[1] += e0 * hi16(va[0]);
            n0[2] += e0 * lo16(va[1]); n0[3] += e0 * hi16(va[1]);
            n1[0] += e1 * lo16(va[2]); n1[1] += e1 * hi16(va[2]);
            n1[2] += e1 * lo16(va[3]); n1[3] += e1 * hi16(va[3]);
            n2[0] += e2 * lo16(vb[0]); n2[1] += e2 * hi16(vb[0]);
            n2[2] += e2 * lo16(vb[1]); n2[3] += e2 * hi16(vb[1]);
            n3[0] += e3 * lo16(vb[2]); n3[1] += e3 * hi16(vb[2]);
            n3[2] += e3 * lo16(vb[3]); n3[3] += e3 * hi16(vb[3]);
        }
        const int c0 = 4 * p;
        float tmsg[4];
        if (r1 > r0) {
            float i0 = 0.25f / den0, i1 = 0.25f / den1, i2 = 0.25f / den2, i3 = 0.25f / den3;
#pragma unroll
            for (int i = 0; i < 4; ++i)
                tmsg[i] = n0[i] * i0 + n1[i] * i1 + n2[i] * i2 + n3[i] * i3 + biasl[c0 + i];
        } else {
#pragma unroll
            for (int i = 0; i < 4; ++i) tmsg[i] = biasl[c0 + i];
        }
        __syncthreads();   // xwB fully staged
        const int wave = __builtin_amdgcn_readfirstlane(tid >> 6);
        const int lane = tid & 63, q = lane >> 4, n = lane & 15;
        u32x4_t ax0 = *(const u32x4_t*)&xwB[n * 36 + q * 4];
        u32x4_t ax1 = *(const u32x4_t*)&xwB[n * 36 + 16 + q * 4];
        f32x4_t acc = {0, 0, 0, 0};
        asm volatile("s_nop 3" : "+v"(ax0), "+v"(ax1), "+v"(acc));
        mfma_bf16(acc, ax0, fw[wave * 64 + lane]);
        mfma_bf16(acc, ax1, fw[(4 + wave) * 64 + lane]);
        asm volatile("s_nop 7\n\ts_nop 7" : "+v"(acc));
#pragma unroll
        for (int reg = 0; reg < 4; ++reg)
            dl[(q * 4 + reg) * 68 + wave * 16 + n] = acc[reg];
        __syncthreads();
        float4 dv = *(const float4*)&dl[wl * 68 + c0];
        float t0 = tmsg[0] + dv.x;
        float t1 = tmsg[1] + dv.y;
        float t2 = tmsg[2] + dv.z;
        float t3 = tmsg[3] + dv.w;
        float pr = fmaxf(t0, 0.f) * wgl[c0] + fmaxf(t1, 0.f) * wgl[c0 + 1] +
                   fmaxf(t2, 0.f) * wgl[c0 + 2] + fmaxf(t3, 0.f) * wgl[c0 + 3];
        pr += __shfl_xor(pr, 1, 64);
        pr += __shfl_xor(pr, 2, 64);
        pr += __shfl_xor(pr, 4, 64);
        pr += __shfl_xor(pr, 8, 64);
        if (p == 0) res[wl] = pr + bg[0];
        __syncthreads();
        if (tid < 16) {
            float v = res[tid];
            out[gb * 16 + tid] = v > 0.f ? v : 0.01f * v;
        }
    }
}

// ---------------------------------------------------------------------------
extern "C" void kernel_launch(void* const* d_in, const int* in_sizes, int n_in,
                              void* d_out, int out_size, void* d_ws, size_t ws_size,
                              hipStream_t stream)
{
    const float* x_sites    = (const float*)d_in[0];
    const float* x_wells    = (const float*)d_in[1];
    const int*   e_sw_src   = (const int*)d_in[2];
    const int*   e_sw_dst   = (const int*)d_in[3];
    const int*   e_ws_src   = (const int*)d_in[4];
    const int*   e_ws_dst   = (const int*)d_in[5];
    const float* W_sw       = (const float*)d_in[6];
    const float* att_src_sw = (const float*)d_in[7];
    const float* att_dst_sw = (const float*)d_in[8];
    const float* b_sw       = (const float*)d_in[9];
    const float* Wl_ws      = (const float*)d_in[10];
    const float* bl_ws      = (const float*)d_in[11];
    const float* Wr_ws      = (const float*)d_in[12];
    const float* W_ss       = (const float*)d_in[13];
    // d_in[14], d_in[15]: att_*_ss cancel (softmax over single self edge == 1)
    const float* b_ss       = (const float*)d_in[16];
    const float* Wl_ww      = (const float*)d_in[17];
    const float* bl_ww      = (const float*)d_in[18];
    const float* Wr_ww      = (const float*)d_in[19];
    const float* Wg         = (const float*)d_in[20];
    const float* bg         = (const float*)d_in[21];
    const float* Wsit       = (const float*)d_in[22];
    const float* bsit       = (const float*)d_in[23];
    float* out = (float*)d_out;

    // workspace layout
    unsigned short* xs = (unsigned short*)d_ws;            // NS*256 bf16 (permuted)
    float* al_s = (float*)(xs + (size_t)NS_ * 256);        // NS*4
    float* vd   = al_s + (size_t)NS_ * 4;                  // 256
    float* vs   = vd + 256;                                // 256
    u32x4_t* fw = (u32x4_t*)(vs + 256);                    // 512  (8 KB)
    u32x4_t* fs = fw + 512;                                // 1024 (16 KB)
    u32x4_t* fsp= fs + 1024;                               // 2048 (32 KB)
    int* ip     = (int*)(fsp + 2048);
    int* h_sw   = ip;                                      // NW   (zeroed)
    int* h_ws   = h_sw + NW_;                              // NS   (zeroed, adjacent)
    int* rp_sw  = h_ws + NS_;                              // NW+4
    int* cur_sw = rp_sw + NW_ + 4;                         // NW
    int* csr_sw = cur_sw + NW_;                            // E
    int* bs_sw  = csr_sw + NE_;                            // 256
    int* rp_ws  = bs_sw + 256;                             // NS+4
    int* cur_ws = rp_ws + NS_ + 4;                         // NS
    int* csr_ws = cur_ws + NS_;                            // E
    int* bs_ws  = csr_ws + NE_;                            // 256

    hipMemsetAsync(h_sw, 0, (size_t)(NW_ + NS_) * sizeof(int), stream);

    const int egrid = (NE_ + 255) / 256;
    const int nb_sw = (NW_ + EPB - 1) / EPB;   // 196
    const int nb_ws = (NS_ + EPB - 1) / EPB;   // 49

    hipLaunchKernelGGL(k_prep, dim3(15), dim3(256), 0, stream,
                       W_sw, att_src_sw, att_dst_sw, Wl_ww, Wr_ww, Wl_ws, Wr_ws, W_ss,
                       vd, vs, fw, fs, fsp);

    hipLaunchKernelGGL(k_hist2, dim3(egrid, 2), dim3(256), 0, stream,
                       e_sw_dst, h_sw, e_ws_dst, h_ws);
    hipLaunchKernelGGL(k_scan1_2, dim3(nb_sw + nb_ws), dim3(256), 0, stream,
                       h_sw, NW_, bs_sw, nb_sw, h_ws, NS_, bs_ws);
    hipLaunchKernelGGL(k_scan2_2, dim3(2), dim3(256), 0, stream,
                       bs_sw, nb_sw, bs_ws, nb_ws);
    hipLaunchKernelGGL(k_scan3_2, dim3(nb_sw + nb_ws), dim3(256), 0, stream,
                       h_sw, NW_, bs_sw, rp_sw, cur_sw, nb_sw,
                       h_ws, NS_, bs_ws, rp_ws, cur_ws);
    hipLaunchKernelGGL(k_scatter2, dim3(egrid, 2), dim3(256), 0, stream,
                       e_sw_src, e_sw_dst, cur_sw, csr_sw,
                       e_ws_src, e_ws_dst, cur_ws, csr_ws);

    hipLaunchKernelGGL(k_sites_pre, dim3((NS_ + 63) / 64), dim3(256), 0, stream,
                       x_sites, fsp, vs, xs, al_s);

    hipLaunchKernelGGL(k_fin, dim3(SAGE_BLKS + GAT_BLKS), dim3(256), 0, stream,
                       x_sites, x_wells, rp_ws, csr_ws, fs, bl_ws, b_ss, Wsit, bsit,
                       vd, rp_sw, csr_sw, al_s, xs, b_sw, bl_ww, fw, Wg, bg, out);
}

// Round 8
// 452.341 us; speedup vs baseline: 1.0650x; 1.0408x over previous
//
#include <hip/hip_runtime.h>

#define NS_ 100000
#define NW_ 400000
#define NE_ 500000
#define EPB 2048   // elements per scan block

#define SAGE_BLKS (NS_ / 16)              // 6250
#define GAT_BLKS  (NW_ / 16)              // 25000

typedef float f32x4_t __attribute__((ext_vector_type(4)));
typedef unsigned u32x4_t __attribute__((ext_vector_type(4)));

__device__ __forceinline__ float lrelu02(float x) { return x > 0.f ? x : 0.2f * x; }
__device__ __forceinline__ float bf2f(unsigned short u) {
    return __uint_as_float(((unsigned)u) << 16);
}
__device__ __forceinline__ unsigned short f2bf(float f) {
    unsigned u = __float_as_uint(f);
    u += 0x7FFFu + ((u >> 16) & 1u);           // round-to-nearest-even
    return (unsigned short)(u >> 16);
}
__device__ __forceinline__ unsigned pk(float lo, float hi) {
    return (unsigned)f2bf(lo) | ((unsigned)f2bf(hi) << 16);
}
// D = A*B + D, 16x16x32 bf16. a/b = 8 bf16 packed in 4 dwords (k ascending).
// A[m=lane&15][k=(lane>>4)*8+j]; B[k=(lane>>4)*8+j][n=lane&15];
// D: col=lane&15, row=(lane>>4)*4+reg.   (layout HW-verified earlier)
__device__ __forceinline__ void mfma_bf16(f32x4_t& acc, u32x4_t a, u32x4_t b) {
    asm volatile("v_mfma_f32_16x16x32_bf16 %0, %1, %2, %0" : "+v"(acc) : "v"(a), "v"(b));
}

// ---------------------------------------------------------------------------
// Prep (15 blocks): vd/vs attention vectors + all weight B-fragments.
// bid 0    : vd/vs
// bid 1-2  : fw  (512)  Wc = Wl_ww + Wr_ww               (wells dense, K=64)
// bid 3-6  : fs  (1024) Wl_ws | Wr_ws + mean W_ss        (sites dense, K=128)
// bid 7-14 : fgw (2048) B[h*64+k, c] = W_sw[k, h*64+c]   (agg dense, K=256)
// ---------------------------------------------------------------------------
__global__ void __launch_bounds__(256)
k_prep(const float* __restrict__ W_sw, const float* __restrict__ att_src,
       const float* __restrict__ att_dst,
       const float* __restrict__ Wl_ww, const float* __restrict__ Wr_ww,
       const float* __restrict__ Wl_ws, const float* __restrict__ Wr_ws,
       const float* __restrict__ W_ss,
       float* __restrict__ vd, float* __restrict__ vs,
       u32x4_t* __restrict__ fw, u32x4_t* __restrict__ fs,
       u32x4_t* __restrict__ fgw)
{
    const int tid = threadIdx.x;
    const int bid = blockIdx.x;
    if (bid == 0) {
        // vd (att_dst) / vs (att_src): v[d*4+h] = sum_c W_sw[d,h*64+c]*att[h,c]
        int d = tid >> 2, h = tid & 3;
        const float4* wp = (const float4*)(W_sw + d * 256 + h * 64);
        const float4* ad = (const float4*)(att_dst + h * 64);
        const float4* as = (const float4*)(att_src + h * 64);
        float accd = 0.f, accs = 0.f;
#pragma unroll
        for (int c = 0; c < 16; ++c) {
            float4 wv = wp[c]; float4 dv = ad[c]; float4 sv = as[c];
            accd += wv.x * dv.x + wv.y * dv.y + wv.z * dv.z + wv.w * dv.w;
            accs += wv.x * sv.x + wv.y * sv.y + wv.z * sv.z + wv.w * sv.w;
        }
        vd[d * 4 + h] = accd;
        vs[d * 4 + h] = accs;
    } else if (bid <= 2) {
        int idx = (bid - 1) * 256 + tid;           // [0,512)
        int f = idx >> 6, lane = idx & 63;
        int kc = f >> 2, ct = f & 3, q = lane >> 4, n = lane & 15;
        int c = ct * 16 + n;
        u32x4_t d;
#pragma unroll
        for (int i = 0; i < 4; ++i) {
            int k = kc * 32 + q * 8 + 2 * i;
            d[i] = pk(Wl_ww[k * 64 + c] + Wr_ww[k * 64 + c],
                      Wl_ww[(k + 1) * 64 + c] + Wr_ww[(k + 1) * 64 + c]);
        }
        fw[idx] = d;
    } else if (bid <= 6) {
        int idx = (bid - 3) * 256 + tid;           // [0,1024)
        int f = idx >> 6, lane = idx & 63;
        int kc = f >> 2, ct = f & 3, q = lane >> 4, n = lane & 15;
        int c = ct * 16 + n;
        u32x4_t d;
#pragma unroll
        for (int i = 0; i < 4; ++i) {
            int k = kc * 32 + q * 8 + 2 * i;
            float lo, hi;
            if (k < 64) {
                lo = Wl_ws[k * 64 + c];
                hi = Wl_ws[(k + 1) * 64 + c];
            } else {
                int kk = k - 64;
                lo = Wr_ws[kk * 64 + c] + 0.25f * (W_ss[kk * 256 + c] + W_ss[kk * 256 + 64 + c] +
                                                   W_ss[kk * 256 + 128 + c] + W_ss[kk * 256 + 192 + c]);
                hi = Wr_ws[(kk + 1) * 64 + c] + 0.25f * (W_ss[(kk + 1) * 256 + c] + W_ss[(kk + 1) * 256 + 64 + c] +
                                                         W_ss[(kk + 1) * 256 + 128 + c] + W_ss[(kk + 1) * 256 + 192 + c]);
            }
            d[i] = pk(lo, hi);
        }
        fs[idx] = d;
    } else {
        int idx = (bid - 7) * 256 + tid;           // [0,2048)
        int f = idx >> 6, lane = idx & 63;
        int kc = f >> 2, ct = f & 3, q = lane >> 4, n = lane & 15;
        int c = ct * 16 + n;
        u32x4_t d;
#pragma unroll
        for (int i = 0; i < 4; ++i) {
            int kk = kc * 32 + q * 8 + 2 * i;      // K index in [0,256): h*64 + k0
            int h = kk >> 6, k0 = kk & 63;         // kk even -> kk+1 same h
            d[i] = pk(W_sw[k0 * 256 + h * 64 + c], W_sw[(k0 + 1) * 256 + h * 64 + c]);
        }
        fgw[idx] = d;
    }
}

// ---------------------------------------------------------------------------
// Sites pre: al_s = x_sites @ vs (exact f32) + bf16 cast xbf of x_sites.
// 64 sites/block, 4 lanes/site (16 ch each). Pure streaming (~40 MB).
// ---------------------------------------------------------------------------
__global__ void __launch_bounds__(256)
k_sites_al(const float* __restrict__ x_sites, const float* __restrict__ vs,
           unsigned short* __restrict__ xbf, float* __restrict__ al_s)
{
    __shared__ float vsl[256];
    const int tid = threadIdx.x;
    vsl[tid] = vs[tid];
    __syncthreads();
    const int s = blockIdx.x * 64 + (tid >> 2);
    const int qq = tid & 3;
    if (s >= NS_) return;   // 4-lane groups exit together (same s)
    const float* xr = x_sites + (size_t)s * 64 + qq * 16;
    float4 a = *(const float4*)(xr);
    float4 b = *(const float4*)(xr + 4);
    float4 c = *(const float4*)(xr + 8);
    float4 d = *(const float4*)(xr + 12);
    float pa[4];
#pragma unroll
    for (int h = 0; h < 4; ++h) {
        const float* v = &vsl[(qq * 16) * 4 + h];
        pa[h] = a.x * v[0]  + a.y * v[4]  + a.z * v[8]  + a.w * v[12]
              + b.x * v[16] + b.y * v[20] + b.z * v[24] + b.w * v[28]
              + c.x * v[32] + c.y * v[36] + c.z * v[40] + c.w * v[44]
              + d.x * v[48] + d.y * v[52] + d.z * v[56] + d.w * v[60];
    }
#pragma unroll
    for (int h = 0; h < 4; ++h) {
        pa[h] += __shfl_xor(pa[h], 1, 64);
        pa[h] += __shfl_xor(pa[h], 2, 64);
    }
    if (qq == 0)
        *(float4*)(al_s + (size_t)s * 4) = make_float4(pa[0], pa[1], pa[2], pa[3]);
    u32x4_t lo = { pk(a.x, a.y), pk(a.z, a.w), pk(b.x, b.y), pk(b.z, b.w) };
    u32x4_t hi = { pk(c.x, c.y), pk(c.z, c.w), pk(d.x, d.y), pk(d.z, d.w) };
    unsigned short* xo = xbf + (size_t)s * 64 + qq * 16;
    *(u32x4_t*)(xo) = lo;
    *(u32x4_t*)(xo + 8) = hi;
}

// ---------------------------------------------------------------------------
// CSR build: histogram -> 3-phase scan -> scatter (relations merged per launch)
// ---------------------------------------------------------------------------
__global__ void __launch_bounds__(256)
k_hist2(const int* __restrict__ d1, int* __restrict__ h1,
        const int* __restrict__ d2, int* __restrict__ h2)
{
    int e = blockIdx.x * 256 + threadIdx.x;
    if (e >= NE_) return;
    if (blockIdx.y == 0) atomicAdd(&h1[d1[e]], 1);
    else                 atomicAdd(&h2[d2[e]], 1);
}

__global__ void __launch_bounds__(256)
k_scan1_2(const int* __restrict__ h1, int n1, int* __restrict__ b1, int nb1,
          const int* __restrict__ h2, int n2, int* __restrict__ b2)
{
    __shared__ int red[256];
    const int tid = threadIdx.x;
    const int bx = blockIdx.x;
    const int* hist; int n; int* bsum; int blk;
    if (bx < nb1) { hist = h1; n = n1; bsum = b1; blk = bx; }
    else          { hist = h2; n = n2; bsum = b2; blk = bx - nb1; }
    int base = blk * EPB + tid * 8;
    int s = 0;
#pragma unroll
    for (int i = 0; i < 8; ++i) { int idx = base + i; if (idx < n) s += hist[idx]; }
    red[tid] = s;
    __syncthreads();
    for (int off = 128; off > 0; off >>= 1) {
        if (tid < off) red[tid] += red[tid + off];
        __syncthreads();
    }
    if (tid == 0) bsum[blk] = red[0];
}

__global__ void __launch_bounds__(256)
k_scan2_2(int* __restrict__ b1, int nb1, int* __restrict__ b2, int nb2)
{
    __shared__ int sh[256];
    const int tid = threadIdx.x;
    int* bsum = blockIdx.x == 0 ? b1 : b2;
    int nb = blockIdx.x == 0 ? nb1 : nb2;
    sh[tid] = (tid < nb) ? bsum[tid] : 0;
    __syncthreads();
    for (int off = 1; off < 256; off <<= 1) {
        int u = (tid >= off) ? sh[tid - off] : 0;
        __syncthreads();
        sh[tid] += u;
        __syncthreads();
    }
    if (tid < nb) bsum[tid] = (tid == 0) ? 0 : sh[tid - 1];
}

__global__ void __launch_bounds__(256)
k_scan3_2(const int* __restrict__ h1, int n1, const int* __restrict__ b1,
          int* __restrict__ rp1, int* __restrict__ cu1, int nb1,
          const int* __restrict__ h2, int n2, const int* __restrict__ b2,
          int* __restrict__ rp2, int* __restrict__ cu2)
{
    __shared__ int tsum[256];
    const int tid = threadIdx.x;
    const int bx = blockIdx.x;
    const int* hist; int n; const int* bsum; int* rowptr; int* cursor; int blk;
    if (bx < nb1) { hist = h1; n = n1; bsum = b1; rowptr = rp1; cursor = cu1; blk = bx; }
    else          { hist = h2; n = n2; bsum = b2; rowptr = rp2; cursor = cu2; blk = bx - nb1; }
    int base = blk * EPB + tid * 8;
    int v[8]; int s = 0;
#pragma unroll
    for (int i = 0; i < 8; ++i) {
        int idx = base + i;
        v[i] = (idx < n) ? hist[idx] : 0;
        s += v[i];
    }
    tsum[tid] = s;
    __syncthreads();
    for (int off = 1; off < 256; off <<= 1) {
        int u = (tid >= off) ? tsum[tid - off] : 0;
        __syncthreads();
        tsum[tid] += u;
        __syncthreads();
    }
    int texcl = tsum[tid] - s;
    int run = bsum[blk] + texcl;
#pragma unroll
    for (int i = 0; i < 8; ++i) {
        int idx = base + i;
        if (idx < n) { rowptr[idx] = run; cursor[idx] = run; run += v[i]; }
    }
    if (blk == 0 && tid == 0) rowptr[n] = NE_;
}

__global__ void __launch_bounds__(256)
k_scatter2(const int* __restrict__ s1, const int* __restrict__ d1,
           int* __restrict__ c1, int* __restrict__ o1,
           const int* __restrict__ s2, const int* __restrict__ d2,
           int* __restrict__ c2, int* __restrict__ o2)
{
    int e = blockIdx.x * 256 + threadIdx.x;
    if (e >= NE_) return;
    if (blockIdx.y == 0) { int p = atomicAdd(&c1[d1[e]], 1); o1[p] = s1[e]; }
    else                 { int p = atomicAdd(&c2[d2[e]], 1); o2[p] = s2[e]; }
}

// ---------------------------------------------------------------------------
// FINAL merged launch (interleaved bid%5): SAGE-sites union GAT-wells.
// GAT body = round-2 structure: gather RAW xbf rows (128 B/edge) + per-head
// f32 weighted sums in-register; dense epilogue = K=64 (x_wells@fw) + K=256
// (agg@fgw) MFMA. All LDS A-tiles rotation-swizzled (col' = (d + 8*row)&31
// within each 32-dword row) -> ds_read_b128 is 2-way (free) instead of 8-way.
// ---------------------------------------------------------------------------
__global__ void __launch_bounds__(256)
k_fin(const float* __restrict__ x_sites, const float* __restrict__ x_wells,
      const int* __restrict__ rp_ws, const int* __restrict__ csr_ws,
      const u32x4_t* __restrict__ fs, const float* __restrict__ bl_ws,
      const float* __restrict__ b_ss, const float* __restrict__ Wsit,
      const float* __restrict__ bsit,
      const float* __restrict__ vd, const int* __restrict__ rp_sw,
      const int* __restrict__ csr_sw, const float* __restrict__ al_s,
      const unsigned short* __restrict__ xbf, const float* __restrict__ b_sw,
      const float* __restrict__ bl_ww, const u32x4_t* __restrict__ fw,
      const u32x4_t* __restrict__ fgw, const float* __restrict__ Wg,
      const float* __restrict__ bg, float* __restrict__ out)
{
    __shared__ float smem[4192];
    const int tid = threadIdx.x;
    const int bid = blockIdx.x;

    if (bid % 5 == 0) {
        // ================= SAGE sites body =================
        const int sb = bid / 5;
        unsigned* mnB = (unsigned*)smem;           // [16][36] swizzled
        unsigned* xB  = (unsigned*)(smem + 576);   // [16][36] swizzled
        float* dl     = smem + 1152;               // [16][68]
        float* biasl  = smem + 2240;               // [64]
        float* wsl    = smem + 2304;               // [64]
        float* res    = smem + 2368;               // [16]
        if (tid < 64) { biasl[tid] = bl_ws[tid] + b_ss[tid]; wsl[tid] = Wsit[tid]; }
        const int sl = tid >> 4, p = tid & 15;
        const int s = sb * 16 + sl;
        const int r0 = rp_ws[s], r1 = rp_ws[s + 1];
        float4 m4 = {0.f, 0.f, 0.f, 0.f};
        for (int j = r0; j < r1; ++j) {
            int wsrc = csr_ws[j];
            float4 xv = ((const float4*)(x_wells + (size_t)wsrc * 64))[p];
            m4.x += xv.x; m4.y += xv.y; m4.z += xv.z; m4.w += xv.w;
        }
        if (r1 > r0) {
            float rc = 1.f / (float)(r1 - r0);
            m4.x *= rc; m4.y *= rc; m4.z *= rc; m4.w *= rc;
        }
        {
            const int c0s = (2 * p + 8 * sl) & 31;     // rotation swizzle
            mnB[sl * 36 + c0s]     = pk(m4.x, m4.y);
            mnB[sl * 36 + c0s + 1] = pk(m4.z, m4.w);
            float4 xv = *(const float4*)(x_sites + (size_t)s * 64 + 4 * p);
            xB[sl * 36 + c0s]     = pk(xv.x, xv.y);
            xB[sl * 36 + c0s + 1] = pk(xv.z, xv.w);
        }
        __syncthreads();
        const int wave = __builtin_amdgcn_readfirstlane(tid >> 6);
        const int lane = tid & 63, q = lane >> 4, n = lane & 15;
        const int b0 = (4 * q + 8 * n) & 31;
        const int b1 = (16 + 4 * q + 8 * n) & 31;
        u32x4_t am0 = *(const u32x4_t*)&mnB[n * 36 + b0];
        u32x4_t am1 = *(const u32x4_t*)&mnB[n * 36 + b1];
        u32x4_t ax0 = *(const u32x4_t*)&xB[n * 36 + b0];
        u32x4_t ax1 = *(const u32x4_t*)&xB[n * 36 + b1];
        f32x4_t acc = {0, 0, 0, 0};
        asm volatile("s_nop 3" : "+v"(am0), "+v"(am1), "+v"(ax0), "+v"(ax1), "+v"(acc));
        mfma_bf16(acc, am0, fs[wave * 64 + lane]);
        mfma_bf16(acc, am1, fs[(4 + wave) * 64 + lane]);
        mfma_bf16(acc, ax0, fs[(8 + wave) * 64 + lane]);
        mfma_bf16(acc, ax1, fs[(12 + wave) * 64 + lane]);
        asm volatile("s_nop 7\n\ts_nop 7" : "+v"(acc));
#pragma unroll
        for (int reg = 0; reg < 4; ++reg)
            dl[(q * 4 + reg) * 68 + wave * 16 + n] = acc[reg];
        __syncthreads();
        const int c0 = 4 * p;
        float4 dv = *(const float4*)&dl[sl * 68 + c0];
        float t0 = dv.x + biasl[c0];
        float t1 = dv.y + biasl[c0 + 1];
        float t2 = dv.z + biasl[c0 + 2];
        float t3 = dv.w + biasl[c0 + 3];
        float pr = fmaxf(t0, 0.f) * wsl[c0] + fmaxf(t1, 0.f) * wsl[c0 + 1] +
                   fmaxf(t2, 0.f) * wsl[c0 + 2] + fmaxf(t3, 0.f) * wsl[c0 + 3];
        pr += __shfl_xor(pr, 1, 64);
        pr += __shfl_xor(pr, 2, 64);
        pr += __shfl_xor(pr, 4, 64);
        pr += __shfl_xor(pr, 8, 64);
        if (p == 0) res[sl] = pr + bsit[0];
        __syncthreads();
        if (tid < 16) {
            float v = res[tid];
            out[(size_t)NW_ + sb * 16 + tid] = v > 0.f ? v : 0.01f * v;
        }
        return;
    }

    // ================= GAT wells body =================
    {
        const int gb = bid - 1 - bid / 5;
        float* vdl    = smem;                       // [16][17]
        unsigned* xwB = (unsigned*)(smem + 272);    // [16][36] swizzled
        unsigned* agB = (unsigned*)(smem + 848);    // [16][132] swizzled (4x32 chunks)
        float* dl     = smem + 2960;                // [16][68]
        float* biasl  = smem + 4048;                // [64]
        float* wgl    = smem + 4112;                // [64]
        float* res    = smem + 4176;                // [16]
        vdl[(tid >> 4) * 17 + (tid & 15)] = vd[tid];
        if (tid < 64) { biasl[tid] = b_sw[tid] + bl_ww[tid]; wgl[tid] = Wg[tid]; }
        __syncthreads();
        const int wl = tid >> 4, p = tid & 15;
        const int w = gb * 16 + wl;
        const int r0 = rp_sw[w], r1 = rp_sw[w + 1];
        const int c0w = (2 * p + 8 * wl) & 31;      // rotation swizzle
        float h0, h1, h2, h3;
        {
            float4 xv = *(const float4*)(x_wells + (size_t)w * 64 + 4 * p);
            xwB[wl * 36 + c0w]     = pk(xv.x, xv.y);
            xwB[wl * 36 + c0w + 1] = pk(xv.z, xv.w);
            const float* vp = &vdl[p * 17];
            h0 = xv.x * vp[0] + xv.y * vp[4] + xv.z * vp[8]  + xv.w * vp[12];
            h1 = xv.x * vp[1] + xv.y * vp[5] + xv.z * vp[9]  + xv.w * vp[13];
            h2 = xv.x * vp[2] + xv.y * vp[6] + xv.z * vp[10] + xv.w * vp[14];
            h3 = xv.x * vp[3] + xv.y * vp[7] + xv.z * vp[11] + xv.w * vp[15];
        }
#pragma unroll
        for (int off = 1; off < 16; off <<= 1) {
            h0 += __shfl_xor(h0, off, 64);
            h1 += __shfl_xor(h1, off, 64);
            h2 += __shfl_xor(h2, off, 64);
            h3 += __shfl_xor(h3, off, 64);
        }
        float den0 = 0, den1 = 0, den2 = 0, den3 = 0;
        // per-head weighted sums of raw x_sites channels 4p..4p+3
        float a00=0,a01=0,a02=0,a03=0, a10=0,a11=0,a12=0,a13=0;
        float a20=0,a21=0,a22=0,a23=0, a30=0,a31=0,a32=0,a33=0;
        for (int j = r0; j < r1; ++j) {
            int s = csr_sw[j];
            float4 as = ((const float4*)al_s)[s];
            ushort4 u = *(const ushort4*)(xbf + (size_t)s * 64 + 4 * p);
            float e0 = __expf(lrelu02(as.x + h0));
            float e1 = __expf(lrelu02(as.y + h1));
            float e2 = __expf(lrelu02(as.z + h2));
            float e3 = __expf(lrelu02(as.w + h3));
            den0 += e0; den1 += e1; den2 += e2; den3 += e3;
            float x0 = bf2f(u.x), x1 = bf2f(u.y), x2 = bf2f(u.z), x3 = bf2f(u.w);
            a00 += e0 * x0; a01 += e0 * x1; a02 += e0 * x2; a03 += e0 * x3;
            a10 += e1 * x0; a11 += e1 * x1; a12 += e1 * x2; a13 += e1 * x3;
            a20 += e2 * x0; a21 += e2 * x1; a22 += e2 * x2; a23 += e2 * x3;
            a30 += e3 * x0; a31 += e3 * x1; a32 += e3 * x2; a33 += e3 * x3;
        }
        if (r1 > r0) {   // fold 1/4 head-mean into the normalize
            float i0 = 0.25f / den0, i1 = 0.25f / den1, i2 = 0.25f / den2, i3 = 0.25f / den3;
            a00 *= i0; a01 *= i0; a02 *= i0; a03 *= i0;
            a10 *= i1; a11 *= i1; a12 *= i1; a13 *= i1;
            a20 *= i2; a21 *= i2; a22 *= i2; a23 *= i2;
            a30 *= i3; a31 *= i3; a32 *= i3; a33 *= i3;
        }
        // stage agg swizzled: chunk h (32 dwords), dword (2p) -> (2p+8*wl)&31
        agB[wl * 132 + 0 * 32 + c0w]     = pk(a00, a01);
        agB[wl * 132 + 0 * 32 + c0w + 1] = pk(a02, a03);
        agB[wl * 132 + 1 * 32 + c0w]     = pk(a10, a11);
        agB[wl * 132 + 1 * 32 + c0w + 1] = pk(a12, a13);
        agB[wl * 132 + 2 * 32 + c0w]     = pk(a20, a21);
        agB[wl * 132 + 2 * 32 + c0w + 1] = pk(a22, a23);
        agB[wl * 132 + 3 * 32 + c0w]     = pk(a30, a31);
        agB[wl * 132 + 3 * 32 + c0w + 1] = pk(a32, a33);
        __syncthreads();
        // ---- dense phase: wave = col-tile ct; A rows = block's 16 wells ----
        const int wave = __builtin_amdgcn_readfirstlane(tid >> 6);
        const int lane = tid & 63, q = lane >> 4, n = lane & 15;
        const int b0 = (4 * q + 8 * n) & 31;
        const int b1 = (16 + 4 * q + 8 * n) & 31;
        u32x4_t ax0 = *(const u32x4_t*)&xwB[n * 36 + b0];
        u32x4_t ax1 = *(const u32x4_t*)&xwB[n * 36 + b1];
        f32x4_t acc = {0, 0, 0, 0};
        asm volatile("s_nop 3" : "+v"(ax0), "+v"(ax1), "+v"(acc));
        mfma_bf16(acc, ax0, fw[wave * 64 + lane]);
        mfma_bf16(acc, ax1, fw[(4 + wave) * 64 + lane]);
#pragma unroll
        for (int kc = 0; kc < 8; ++kc) {
            const int hh = kc >> 1;
            const int sofs = (((kc & 1) * 16) + 4 * q + 8 * n) & 31;
            u32x4_t a = *(const u32x4_t*)&agB[n * 132 + hh * 32 + sofs];
            mfma_bf16(acc, a, fgw[(kc * 4 + wave) * 64 + lane]);
        }
        asm volatile("s_nop 7\n\ts_nop 7" : "+v"(acc));
#pragma unroll
        for (int reg = 0; reg < 4; ++reg)
            dl[(q * 4 + reg) * 68 + wave * 16 + n] = acc[reg];
        __syncthreads();
        const int c0 = 4 * p;
        float4 dv = *(const float4*)&dl[wl * 68 + c0];
        float t0 = dv.x + biasl[c0];
        float t1 = dv.y + biasl[c0 + 1];
        float t2 = dv.z + biasl[c0 + 2];
        float t3 = dv.w + biasl[c0 + 3];
        float pr = fmaxf(t0, 0.f) * wgl[c0] + fmaxf(t1, 0.f) * wgl[c0 + 1] +
                   fmaxf(t2, 0.f) * wgl[c0 + 2] + fmaxf(t3, 0.f) * wgl[c0 + 3];
        pr += __shfl_xor(pr, 1, 64);
        pr += __shfl_xor(pr, 2, 64);
        pr += __shfl_xor(pr, 4, 64);
        pr += __shfl_xor(pr, 8, 64);
        if (p == 0) res[wl] = pr + bg[0];
        __syncthreads();
        if (tid < 16) {
            float v = res[tid];
            out[gb * 16 + tid] = v > 0.f ? v : 0.01f * v;
        }
    }
}

// ---------------------------------------------------------------------------
extern "C" void kernel_launch(void* const* d_in, const int* in_sizes, int n_in,
                              void* d_out, int out_size, void* d_ws, size_t ws_size,
                              hipStream_t stream)
{
    const float* x_sites    = (const float*)d_in[0];
    const float* x_wells    = (const float*)d_in[1];
    const int*   e_sw_src   = (const int*)d_in[2];
    const int*   e_sw_dst   = (const int*)d_in[3];
    const int*   e_ws_src   = (const int*)d_in[4];
    const int*   e_ws_dst   = (const int*)d_in[5];
    const float* W_sw       = (const float*)d_in[6];
    const float* att_src_sw = (const float*)d_in[7];
    const float* att_dst_sw = (const float*)d_in[8];
    const float* b_sw       = (const float*)d_in[9];
    const float* Wl_ws      = (const float*)d_in[10];
    const float* bl_ws      = (const float*)d_in[11];
    const float* Wr_ws      = (const float*)d_in[12];
    const float* W_ss       = (const float*)d_in[13];
    // d_in[14], d_in[15]: att_*_ss cancel (softmax over single self edge == 1)
    const float* b_ss       = (const float*)d_in[16];
    const float* Wl_ww      = (const float*)d_in[17];
    const float* bl_ww      = (const float*)d_in[18];
    const float* Wr_ww      = (const float*)d_in[19];
    const float* Wg         = (const float*)d_in[20];
    const float* bg         = (const float*)d_in[21];
    const float* Wsit       = (const float*)d_in[22];
    const float* bsit       = (const float*)d_in[23];
    float* out = (float*)d_out;

    // workspace layout (round-2 base: xbf = bf16 x_sites copy; no xs projection)
    unsigned short* xbf = (unsigned short*)d_ws;           // NS*64 bf16
    float* al_s = (float*)(xbf + (size_t)NS_ * 64);        // NS*4
    float* vd   = al_s + (size_t)NS_ * 4;                  // 256
    float* vs   = vd + 256;                                // 256
    u32x4_t* fw = (u32x4_t*)(vs + 256);                    // 512  (8 KB)
    u32x4_t* fs = fw + 512;                                // 1024 (16 KB)
    u32x4_t* fgw= fs + 1024;                               // 2048 (32 KB)
    int* ip     = (int*)(fgw + 2048);
    int* h_sw   = ip;                                      // NW   (zeroed)
    int* h_ws   = h_sw + NW_;                              // NS   (zeroed, adjacent)
    int* rp_sw  = h_ws + NS_;                              // NW+4
    int* cur_sw = rp_sw + NW_ + 4;                         // NW
    int* csr_sw = cur_sw + NW_;                            // E
    int* bs_sw  = csr_sw + NE_;                            // 256
    int* rp_ws  = bs_sw + 256;                             // NS+4
    int* cur_ws = rp_ws + NS_ + 4;                         // NS
    int* csr_ws = cur_ws + NS_;                            // E
    int* bs_ws  = csr_ws + NE_;                            // 256

    hipMemsetAsync(h_sw, 0, (size_t)(NW_ + NS_) * sizeof(int), stream);

    const int egrid = (NE_ + 255) / 256;
    const int nb_sw = (NW_ + EPB - 1) / EPB;   // 196
    const int nb_ws = (NS_ + EPB - 1) / EPB;   // 49

    hipLaunchKernelGGL(k_prep, dim3(15), dim3(256), 0, stream,
                       W_sw, att_src_sw, att_dst_sw, Wl_ww, Wr_ww, Wl_ws, Wr_ws, W_ss,
                       vd, vs, fw, fs, fgw);

    hipLaunchKernelGGL(k_hist2, dim3(egrid, 2), dim3(256), 0, stream,
                       e_sw_dst, h_sw, e_ws_dst, h_ws);
    hipLaunchKernelGGL(k_scan1_2, dim3(nb_sw + nb_ws), dim3(256), 0, stream,
                       h_sw, NW_, bs_sw, nb_sw, h_ws, NS_, bs_ws);
    hipLaunchKernelGGL(k_scan2_2, dim3(2), dim3(256), 0, stream,
                       bs_sw, nb_sw, bs_ws, nb_ws);
    hipLaunchKernelGGL(k_scan3_2, dim3(nb_sw + nb_ws), dim3(256), 0, stream,
                       h_sw, NW_, bs_sw, rp_sw, cur_sw, nb_sw,
                       h_ws, NS_, bs_ws, rp_ws, cur_ws);
    hipLaunchKernelGGL(k_scatter2, dim3(egrid, 2), dim3(256), 0, stream,
                       e_sw_src, e_sw_dst, cur_sw, csr_sw,
                       e_ws_src, e_ws_dst, cur_ws, csr_ws);

    hipLaunchKernelGGL(k_sites_al, dim3((NS_ + 63) / 64), dim3(256), 0, stream,
                       x_sites, vs, xbf, al_s);

    hipLaunchKernelGGL(k_fin, dim3(SAGE_BLKS + GAT_BLKS), dim3(256), 0, stream,
                       x_sites, x_wells, rp_ws, csr_ws, fs, bl_ws, b_ss, Wsit, bsit,
                       vd, rp_sw, csr_sw, al_s, xbf, b_sw, bl_ww, fw, fgw,
                       Wg, bg, out);
}

// Round 9
// 447.522 us; speedup vs baseline: 1.0765x; 1.0108x over previous
//
#include <hip/hip_runtime.h>

#define NS_ 100000
#define NW_ 400000
#define NE_ 500000
#define EPB 2048   // elements per scan block

#define SAGE_BLKS (NS_ / 16)              // 6250
#define GAT_BLKS  (NW_ / 16)              // 25000
#define EGRID ((NE_ + 255) / 256)         // 1954
#define SAL_BLKS ((NS_ + 63) / 64)        // 1563

typedef float f32x4_t __attribute__((ext_vector_type(4)));
typedef unsigned u32x4_t __attribute__((ext_vector_type(4)));

__device__ __forceinline__ float lrelu02(float x) { return x > 0.f ? x : 0.2f * x; }
__device__ __forceinline__ float bf2f(unsigned short u) {
    return __uint_as_float(((unsigned)u) << 16);
}
__device__ __forceinline__ unsigned short f2bf(float f) {
    unsigned u = __float_as_uint(f);
    u += 0x7FFFu + ((u >> 16) & 1u);           // round-to-nearest-even
    return (unsigned short)(u >> 16);
}
__device__ __forceinline__ unsigned pk(float lo, float hi) {
    return (unsigned)f2bf(lo) | ((unsigned)f2bf(hi) << 16);
}
// D = A*B + D, 16x16x32 bf16. a/b = 8 bf16 packed in 4 dwords (k ascending).
// A[m=lane&15][k=(lane>>4)*8+j]; B[k=(lane>>4)*8+j][n=lane&15];
// D: col=lane&15, row=(lane>>4)*4+reg.   (layout HW-verified earlier)
__device__ __forceinline__ void mfma_bf16(f32x4_t& acc, u32x4_t a, u32x4_t b) {
    asm volatile("v_mfma_f32_16x16x32_bf16 %0, %1, %2, %0" : "+v"(acc) : "v"(a), "v"(b));
}

// ---------------------------------------------------------------------------
// Prep (15 blocks): vd/vs attention vectors + all weight B-fragments.
// bid 0    : vd/vs
// bid 1-2  : fw  (512)  Wc = Wl_ww + Wr_ww               (wells dense, K=64)
// bid 3-6  : fs  (1024) Wl_ws | Wr_ws + mean W_ss        (sites dense, K=128)
// bid 7-14 : fgw (2048) B[h*64+k, c] = W_sw[k, h*64+c]   (agg dense, K=256)
// ---------------------------------------------------------------------------
__global__ void __launch_bounds__(256)
k_prep(const float* __restrict__ W_sw, const float* __restrict__ att_src,
       const float* __restrict__ att_dst,
       const float* __restrict__ Wl_ww, const float* __restrict__ Wr_ww,
       const float* __restrict__ Wl_ws, const float* __restrict__ Wr_ws,
       const float* __restrict__ W_ss,
       float* __restrict__ vd, float* __restrict__ vs,
       u32x4_t* __restrict__ fw, u32x4_t* __restrict__ fs,
       u32x4_t* __restrict__ fgw)
{
    const int tid = threadIdx.x;
    const int bid = blockIdx.x;
    if (bid == 0) {
        // vd (att_dst) / vs (att_src): v[d*4+h] = sum_c W_sw[d,h*64+c]*att[h,c]
        int d = tid >> 2, h = tid & 3;
        const float4* wp = (const float4*)(W_sw + d * 256 + h * 64);
        const float4* ad = (const float4*)(att_dst + h * 64);
        const float4* as = (const float4*)(att_src + h * 64);
        float accd = 0.f, accs = 0.f;
#pragma unroll
        for (int c = 0; c < 16; ++c) {
            float4 wv = wp[c]; float4 dv = ad[c]; float4 sv = as[c];
            accd += wv.x * dv.x + wv.y * dv.y + wv.z * dv.z + wv.w * dv.w;
            accs += wv.x * sv.x + wv.y * sv.y + wv.z * sv.z + wv.w * sv.w;
        }
        vd[d * 4 + h] = accd;
        vs[d * 4 + h] = accs;
    } else if (bid <= 2) {
        int idx = (bid - 1) * 256 + tid;           // [0,512)
        int f = idx >> 6, lane = idx & 63;
        int kc = f >> 2, ct = f & 3, q = lane >> 4, n = lane & 15;
        int c = ct * 16 + n;
        u32x4_t d;
#pragma unroll
        for (int i = 0; i < 4; ++i) {
            int k = kc * 32 + q * 8 + 2 * i;
            d[i] = pk(Wl_ww[k * 64 + c] + Wr_ww[k * 64 + c],
                      Wl_ww[(k + 1) * 64 + c] + Wr_ww[(k + 1) * 64 + c]);
        }
        fw[idx] = d;
    } else if (bid <= 6) {
        int idx = (bid - 3) * 256 + tid;           // [0,1024)
        int f = idx >> 6, lane = idx & 63;
        int kc = f >> 2, ct = f & 3, q = lane >> 4, n = lane & 15;
        int c = ct * 16 + n;
        u32x4_t d;
#pragma unroll
        for (int i = 0; i < 4; ++i) {
            int k = kc * 32 + q * 8 + 2 * i;
            float lo, hi;
            if (k < 64) {
                lo = Wl_ws[k * 64 + c];
                hi = Wl_ws[(k + 1) * 64 + c];
            } else {
                int kk = k - 64;
                lo = Wr_ws[kk * 64 + c] + 0.25f * (W_ss[kk * 256 + c] + W_ss[kk * 256 + 64 + c] +
                                                   W_ss[kk * 256 + 128 + c] + W_ss[kk * 256 + 192 + c]);
                hi = Wr_ws[(kk + 1) * 64 + c] + 0.25f * (W_ss[(kk + 1) * 256 + c] + W_ss[(kk + 1) * 256 + 64 + c] +
                                                         W_ss[(kk + 1) * 256 + 128 + c] + W_ss[(kk + 1) * 256 + 192 + c]);
            }
            d[i] = pk(lo, hi);
        }
        fs[idx] = d;
    } else {
        int idx = (bid - 7) * 256 + tid;           // [0,2048)
        int f = idx >> 6, lane = idx & 63;
        int kc = f >> 2, ct = f & 3, q = lane >> 4, n = lane & 15;
        int c = ct * 16 + n;
        u32x4_t d;
#pragma unroll
        for (int i = 0; i < 4; ++i) {
            int kk = kc * 32 + q * 8 + 2 * i;      // K index in [0,256): h*64 + k0
            int h = kk >> 6, k0 = kk & 63;         // kk even -> kk+1 same h
            d[i] = pk(W_sw[k0 * 256 + h * 64 + c], W_sw[(k0 + 1) * 256 + h * 64 + c]);
        }
        fgw[idx] = d;
    }
}

// ---------------------------------------------------------------------------
// MERGED: sites_al (al_s = x_sites@vs + bf16 cast xbf) UNION edge histogram.
// Independent bodies; co-residency overlaps streaming with atomic latency.
// ---------------------------------------------------------------------------
__global__ void __launch_bounds__(256)
k_hist_sal(const float* __restrict__ x_sites, const float* __restrict__ vs,
           unsigned short* __restrict__ xbf, float* __restrict__ al_s,
           const int* __restrict__ d1, int* __restrict__ h1,
           const int* __restrict__ d2, int* __restrict__ h2)
{
    const int tid = threadIdx.x;
    const int bid = blockIdx.x;
    if (bid >= SAL_BLKS) {
        // ---- histogram body ----
        int hb = bid - SAL_BLKS;
        int rel = hb / EGRID;
        int e = (hb % EGRID) * 256 + tid;
        if (e < NE_) {
            if (rel == 0) atomicAdd(&h1[d1[e]], 1);
            else          atomicAdd(&h2[d2[e]], 1);
        }
        return;
    }
    // ---- sites_al body ----
    __shared__ float vsl[256];
    vsl[tid] = vs[tid];
    __syncthreads();
    const int s = bid * 64 + (tid >> 2);
    const int qq = tid & 3;
    if (s >= NS_) return;   // 4-lane groups exit together (same s)
    const float* xr = x_sites + (size_t)s * 64 + qq * 16;
    float4 a = *(const float4*)(xr);
    float4 b = *(const float4*)(xr + 4);
    float4 c = *(const float4*)(xr + 8);
    float4 d = *(const float4*)(xr + 12);
    float pa[4];
#pragma unroll
    for (int h = 0; h < 4; ++h) {
        const float* v = &vsl[(qq * 16) * 4 + h];
        pa[h] = a.x * v[0]  + a.y * v[4]  + a.z * v[8]  + a.w * v[12]
              + b.x * v[16] + b.y * v[20] + b.z * v[24] + b.w * v[28]
              + c.x * v[32] + c.y * v[36] + c.z * v[40] + c.w * v[44]
              + d.x * v[48] + d.y * v[52] + d.z * v[56] + d.w * v[60];
    }
#pragma unroll
    for (int h = 0; h < 4; ++h) {
        pa[h] += __shfl_xor(pa[h], 1, 64);
        pa[h] += __shfl_xor(pa[h], 2, 64);
    }
    if (qq == 0)
        *(float4*)(al_s + (size_t)s * 4) = make_float4(pa[0], pa[1], pa[2], pa[3]);
    u32x4_t lo = { pk(a.x, a.y), pk(a.z, a.w), pk(b.x, b.y), pk(b.z, b.w) };
    u32x4_t hi = { pk(c.x, c.y), pk(c.z, c.w), pk(d.x, d.y), pk(d.z, d.w) };
    unsigned short* xo = xbf + (size_t)s * 64 + qq * 16;
    *(u32x4_t*)(xo) = lo;
    *(u32x4_t*)(xo + 8) = hi;
}

// ---------------------------------------------------------------------------
// CSR build: scan1 (raw block sums) -> scan3m (inline block-sum prefix +
// rowptr/cursor) -> scatter.
// ---------------------------------------------------------------------------
__global__ void __launch_bounds__(256)
k_scan1_2(const int* __restrict__ h1, int n1, int* __restrict__ b1, int nb1,
          const int* __restrict__ h2, int n2, int* __restrict__ b2)
{
    __shared__ int red[256];
    const int tid = threadIdx.x;
    const int bx = blockIdx.x;
    const int* hist; int n; int* bsum; int blk;
    if (bx < nb1) { hist = h1; n = n1; bsum = b1; blk = bx; }
    else          { hist = h2; n = n2; bsum = b2; blk = bx - nb1; }
    int base = blk * EPB + tid * 8;
    int s = 0;
#pragma unroll
    for (int i = 0; i < 8; ++i) { int idx = base + i; if (idx < n) s += hist[idx]; }
    red[tid] = s;
    __syncthreads();
    for (int off = 128; off > 0; off >>= 1) {
        if (tid < off) red[tid] += red[tid + off];
        __syncthreads();
    }
    if (tid == 0) bsum[blk] = red[0];
}

// scan3 with inline scan2: each block prefix-sums the raw block sums in LDS.
__global__ void __launch_bounds__(256)
k_scan3m(const int* __restrict__ h1, int n1, const int* __restrict__ b1,
         int* __restrict__ rp1, int* __restrict__ cu1, int nb1,
         const int* __restrict__ h2, int n2, const int* __restrict__ b2,
         int* __restrict__ rp2, int* __restrict__ cu2, int nb2)
{
    __shared__ int tsum[256];
    __shared__ int pre[256];
    const int tid = threadIdx.x;
    const int bx = blockIdx.x;
    const int* hist; int n; const int* bsum; int* rowptr; int* cursor; int blk; int nb;
    if (bx < nb1) { hist = h1; n = n1; bsum = b1; rowptr = rp1; cursor = cu1; blk = bx; nb = nb1; }
    else          { hist = h2; n = n2; bsum = b2; rowptr = rp2; cursor = cu2; blk = bx - nb1; nb = nb2; }
    // inline scan2: inclusive prefix of raw block sums (nb <= 256)
    pre[tid] = (tid < nb) ? bsum[tid] : 0;
    __syncthreads();
    for (int off = 1; off < 256; off <<= 1) {
        int u = (tid >= off) ? pre[tid - off] : 0;
        __syncthreads();
        pre[tid] += u;
        __syncthreads();
    }
    const int blkoff = (blk == 0) ? 0 : pre[blk - 1];
    int base = blk * EPB + tid * 8;
    int v[8]; int s = 0;
#pragma unroll
    for (int i = 0; i < 8; ++i) {
        int idx = base + i;
        v[i] = (idx < n) ? hist[idx] : 0;
        s += v[i];
    }
    tsum[tid] = s;
    __syncthreads();
    for (int off = 1; off < 256; off <<= 1) {
        int u = (tid >= off) ? tsum[tid - off] : 0;
        __syncthreads();
        tsum[tid] += u;
        __syncthreads();
    }
    int texcl = tsum[tid] - s;
    int run = blkoff + texcl;
#pragma unroll
    for (int i = 0; i < 8; ++i) {
        int idx = base + i;
        if (idx < n) { rowptr[idx] = run; cursor[idx] = run; run += v[i]; }
    }
    if (blk == 0 && tid == 0) rowptr[n] = NE_;
}

__global__ void __launch_bounds__(256)
k_scatter2(const int* __restrict__ s1, const int* __restrict__ d1,
           int* __restrict__ c1, int* __restrict__ o1,
           const int* __restrict__ s2, const int* __restrict__ d2,
           int* __restrict__ c2, int* __restrict__ o2)
{
    int e = blockIdx.x * 256 + threadIdx.x;
    if (e >= NE_) return;
    if (blockIdx.y == 0) { int p = atomicAdd(&c1[d1[e]], 1); o1[p] = s1[e]; }
    else                 { int p = atomicAdd(&c2[d2[e]], 1); o2[p] = s2[e]; }
}

// ---------------------------------------------------------------------------
// FINAL merged launch (interleaved bid%5): SAGE-sites union GAT-wells.
// GAT body: gather RAW xbf rows + per-head f32 weighted sums; dense = K=64
// (x_wells@fw) + K=256 (agg@fgw) MFMA. Gather loops are 2-edge unrolled with
// index prefetch (halves the serial csr->payload chains); all LDS A-tile
// staging uses uint2 (b64) stores spanning even+odd banks.
// ---------------------------------------------------------------------------
__global__ void __launch_bounds__(256)
k_fin(const float* __restrict__ x_sites, const float* __restrict__ x_wells,
      const int* __restrict__ rp_ws, const int* __restrict__ csr_ws,
      const u32x4_t* __restrict__ fs, const float* __restrict__ bl_ws,
      const float* __restrict__ b_ss, const float* __restrict__ Wsit,
      const float* __restrict__ bsit,
      const float* __restrict__ vd, const int* __restrict__ rp_sw,
      const int* __restrict__ csr_sw, const float* __restrict__ al_s,
      const unsigned short* __restrict__ xbf, const float* __restrict__ b_sw,
      const float* __restrict__ bl_ww, const u32x4_t* __restrict__ fw,
      const u32x4_t* __restrict__ fgw, const float* __restrict__ Wg,
      const float* __restrict__ bg, float* __restrict__ out)
{
    __shared__ float smem[4192];
    const int tid = threadIdx.x;
    const int bid = blockIdx.x;

    if (bid % 5 == 0) {
        // ================= SAGE sites body =================
        const int sb = bid / 5;
        unsigned* mnB = (unsigned*)smem;           // [16][36] swizzled
        unsigned* xB  = (unsigned*)(smem + 576);   // [16][36] swizzled
        float* dl     = smem + 1152;               // [16][68]
        float* biasl  = smem + 2240;               // [64]
        float* wsl    = smem + 2304;               // [64]
        float* res    = smem + 2368;               // [16]
        if (tid < 64) { biasl[tid] = bl_ws[tid] + b_ss[tid]; wsl[tid] = Wsit[tid]; }
        const int sl = tid >> 4, p = tid & 15;
        const int s = sb * 16 + sl;
        const int r0 = rp_ws[s], r1 = rp_ws[s + 1];
        int sA = csr_ws[min(r0, NE_ - 1)];
        int sB = csr_ws[min(r0 + 1, NE_ - 1)];
        float4 m4 = {0.f, 0.f, 0.f, 0.f};
        int j = r0;
        for (; j + 2 <= r1; j += 2) {
            float4 xv0 = ((const float4*)(x_wells + (size_t)sA * 64))[p];
            float4 xv1 = ((const float4*)(x_wells + (size_t)sB * 64))[p];
            int sN0 = csr_ws[min(j + 2, NE_ - 1)];
            int sN1 = csr_ws[min(j + 3, NE_ - 1)];
            m4.x += xv0.x; m4.y += xv0.y; m4.z += xv0.z; m4.w += xv0.w;
            m4.x += xv1.x; m4.y += xv1.y; m4.z += xv1.z; m4.w += xv1.w;
            sA = sN0; sB = sN1;
        }
        if (j < r1) {
            float4 xv0 = ((const float4*)(x_wells + (size_t)sA * 64))[p];
            m4.x += xv0.x; m4.y += xv0.y; m4.z += xv0.z; m4.w += xv0.w;
        }
        if (r1 > r0) {
            float rc = 1.f / (float)(r1 - r0);
            m4.x *= rc; m4.y *= rc; m4.z *= rc; m4.w *= rc;
        }
        {
            const int c0s = (2 * p + 8 * sl) & 31;     // rotation swizzle
            *(uint2*)&mnB[sl * 36 + c0s] = make_uint2(pk(m4.x, m4.y), pk(m4.z, m4.w));
            float4 xv = *(const float4*)(x_sites + (size_t)s * 64 + 4 * p);
            *(uint2*)&xB[sl * 36 + c0s]  = make_uint2(pk(xv.x, xv.y), pk(xv.z, xv.w));
        }
        __syncthreads();
        const int wave = __builtin_amdgcn_readfirstlane(tid >> 6);
        const int lane = tid & 63, q = lane >> 4, n = lane & 15;
        const int b0 = (4 * q + 8 * n) & 31;
        const int b1 = (16 + 4 * q + 8 * n) & 31;
        u32x4_t am0 = *(const u32x4_t*)&mnB[n * 36 + b0];
        u32x4_t am1 = *(const u32x4_t*)&mnB[n * 36 + b1];
        u32x4_t ax0 = *(const u32x4_t*)&xB[n * 36 + b0];
        u32x4_t ax1 = *(const u32x4_t*)&xB[n * 36 + b1];
        f32x4_t acc = {0, 0, 0, 0};
        asm volatile("s_nop 3" : "+v"(am0), "+v"(am1), "+v"(ax0), "+v"(ax1), "+v"(acc));
        mfma_bf16(acc, am0, fs[wave * 64 + lane]);
        mfma_bf16(acc, am1, fs[(4 + wave) * 64 + lane]);
        mfma_bf16(acc, ax0, fs[(8 + wave) * 64 + lane]);
        mfma_bf16(acc, ax1, fs[(12 + wave) * 64 + lane]);
        asm volatile("s_nop 7\n\ts_nop 7" : "+v"(acc));
#pragma unroll
        for (int reg = 0; reg < 4; ++reg)
            dl[(q * 4 + reg) * 68 + wave * 16 + n] = acc[reg];
        __syncthreads();
        const int c0 = 4 * p;
        float4 dv = *(const float4*)&dl[sl * 68 + c0];
        float t0 = dv.x + biasl[c0];
        float t1 = dv.y + biasl[c0 + 1];
        float t2 = dv.z + biasl[c0 + 2];
        float t3 = dv.w + biasl[c0 + 3];
        float pr = fmaxf(t0, 0.f) * wsl[c0] + fmaxf(t1, 0.f) * wsl[c0 + 1] +
                   fmaxf(t2, 0.f) * wsl[c0 + 2] + fmaxf(t3, 0.f) * wsl[c0 + 3];
        pr += __shfl_xor(pr, 1, 64);
        pr += __shfl_xor(pr, 2, 64);
        pr += __shfl_xor(pr, 4, 64);
        pr += __shfl_xor(pr, 8, 64);
        if (p == 0) res[sl] = pr + bsit[0];
        __syncthreads();
        if (tid < 16) {
            float v = res[tid];
            out[(size_t)NW_ + sb * 16 + tid] = v > 0.f ? v : 0.01f * v;
        }
        return;
    }

    // ================= GAT wells body =================
    {
        const int gb = bid - 1 - bid / 5;
        float* vdl    = smem;                       // [16][17]
        unsigned* xwB = (unsigned*)(smem + 272);    // [16][36] swizzled
        unsigned* agB = (unsigned*)(smem + 848);    // [16][132] swizzled (4x32 chunks)
        float* dl     = smem + 2960;                // [16][68]
        float* biasl  = smem + 4048;                // [64]
        float* wgl    = smem + 4112;                // [64]
        float* res    = smem + 4176;                // [16]
        vdl[(tid >> 4) * 17 + (tid & 15)] = vd[tid];
        if (tid < 64) { biasl[tid] = b_sw[tid] + bl_ww[tid]; wgl[tid] = Wg[tid]; }
        __syncthreads();
        const int wl = tid >> 4, p = tid & 15;
        const int w = gb * 16 + wl;
        const int r0 = rp_sw[w], r1 = rp_sw[w + 1];
        int sA = csr_sw[min(r0, NE_ - 1)];
        int sB = csr_sw[min(r0 + 1, NE_ - 1)];
        const int c0w = (2 * p + 8 * wl) & 31;      // rotation swizzle
        float h0, h1, h2, h3;
        {
            float4 xv = *(const float4*)(x_wells + (size_t)w * 64 + 4 * p);
            *(uint2*)&xwB[wl * 36 + c0w] = make_uint2(pk(xv.x, xv.y), pk(xv.z, xv.w));
            const float* vp = &vdl[p * 17];
            h0 = xv.x * vp[0] + xv.y * vp[4] + xv.z * vp[8]  + xv.w * vp[12];
            h1 = xv.x * vp[1] + xv.y * vp[5] + xv.z * vp[9]  + xv.w * vp[13];
            h2 = xv.x * vp[2] + xv.y * vp[6] + xv.z * vp[10] + xv.w * vp[14];
            h3 = xv.x * vp[3] + xv.y * vp[7] + xv.z * vp[11] + xv.w * vp[15];
        }
#pragma unroll
        for (int off = 1; off < 16; off <<= 1) {
            h0 += __shfl_xor(h0, off, 64);
            h1 += __shfl_xor(h1, off, 64);
            h2 += __shfl_xor(h2, off, 64);
            h3 += __shfl_xor(h3, off, 64);
        }
        float den0 = 0, den1 = 0, den2 = 0, den3 = 0;
        // per-head weighted sums of raw x_sites channels 4p..4p+3
        float a00=0,a01=0,a02=0,a03=0, a10=0,a11=0,a12=0,a13=0;
        float a20=0,a21=0,a22=0,a23=0, a30=0,a31=0,a32=0,a33=0;
        auto EDGE = [&](float4 as, ushort4 u) {
            float e0 = __expf(lrelu02(as.x + h0));
            float e1 = __expf(lrelu02(as.y + h1));
            float e2 = __expf(lrelu02(as.z + h2));
            float e3 = __expf(lrelu02(as.w + h3));
            den0 += e0; den1 += e1; den2 += e2; den3 += e3;
            float x0 = bf2f(u.x), x1 = bf2f(u.y), x2 = bf2f(u.z), x3 = bf2f(u.w);
            a00 += e0 * x0; a01 += e0 * x1; a02 += e0 * x2; a03 += e0 * x3;
            a10 += e1 * x0; a11 += e1 * x1; a12 += e1 * x2; a13 += e1 * x3;
            a20 += e2 * x0; a21 += e2 * x1; a22 += e2 * x2; a23 += e2 * x3;
            a30 += e3 * x0; a31 += e3 * x1; a32 += e3 * x2; a33 += e3 * x3;
        };
        int j = r0;
        for (; j + 2 <= r1; j += 2) {
            float4 as0 = ((const float4*)al_s)[sA];
            ushort4 u0 = *(const ushort4*)(xbf + (size_t)sA * 64 + 4 * p);
            float4 as1 = ((const float4*)al_s)[sB];
            ushort4 u1 = *(const ushort4*)(xbf + (size_t)sB * 64 + 4 * p);
            int sN0 = csr_sw[min(j + 2, NE_ - 1)];
            int sN1 = csr_sw[min(j + 3, NE_ - 1)];
            EDGE(as0, u0);
            EDGE(as1, u1);
            sA = sN0; sB = sN1;
        }
        if (j < r1) {
            float4 as0 = ((const float4*)al_s)[sA];
            ushort4 u0 = *(const ushort4*)(xbf + (size_t)sA * 64 + 4 * p);
            EDGE(as0, u0);
        }
        if (r1 > r0) {   // fold 1/4 head-mean into the normalize
            float i0 = 0.25f / den0, i1 = 0.25f / den1, i2 = 0.25f / den2, i3 = 0.25f / den3;
            a00 *= i0; a01 *= i0; a02 *= i0; a03 *= i0;
            a10 *= i1; a11 *= i1; a12 *= i1; a13 *= i1;
            a20 *= i2; a21 *= i2; a22 *= i2; a23 *= i2;
            a30 *= i3; a31 *= i3; a32 *= i3; a33 *= i3;
        }
        // stage agg swizzled, uint2 stores (even+odd bank spans)
        *(uint2*)&agB[wl * 132 + 0 * 32 + c0w] = make_uint2(pk(a00, a01), pk(a02, a03));
        *(uint2*)&agB[wl * 132 + 1 * 32 + c0w] = make_uint2(pk(a10, a11), pk(a12, a13));
        *(uint2*)&agB[wl * 132 + 2 * 32 + c0w] = make_uint2(pk(a20, a21), pk(a22, a23));
        *(uint2*)&agB[wl * 132 + 3 * 32 + c0w] = make_uint2(pk(a30, a31), pk(a32, a33));
        __syncthreads();
        // ---- dense phase: wave = col-tile ct; A rows = block's 16 wells ----
        const int wave = __builtin_amdgcn_readfirstlane(tid >> 6);
        const int lane = tid & 63, q = lane >> 4, n = lane & 15;
        const int b0 = (4 * q + 8 * n) & 31;
        const int b1 = (16 + 4 * q + 8 * n) & 31;
        u32x4_t ax0 = *(const u32x4_t*)&xwB[n * 36 + b0];
        u32x4_t ax1 = *(const u32x4_t*)&xwB[n * 36 + b1];
        f32x4_t acc = {0, 0, 0, 0};
        asm volatile("s_nop 3" : "+v"(ax0), "+v"(ax1), "+v"(acc));
        mfma_bf16(acc, ax0, fw[wave * 64 + lane]);
        mfma_bf16(acc, ax1, fw[(4 + wave) * 64 + lane]);
#pragma unroll
        for (int kc = 0; kc < 8; ++kc) {
            const int hh = kc >> 1;
            const int sofs = (((kc & 1) * 16) + 4 * q + 8 * n) & 31;
            u32x4_t a = *(const u32x4_t*)&agB[n * 132 + hh * 32 + sofs];
            mfma_bf16(acc, a, fgw[(kc * 4 + wave) * 64 + lane]);
        }
        asm volatile("s_nop 7\n\ts_nop 7" : "+v"(acc));
#pragma unroll
        for (int reg = 0; reg < 4; ++reg)
            dl[(q * 4 + reg) * 68 + wave * 16 + n] = acc[reg];
        __syncthreads();
        const int c0 = 4 * p;
        float4 dv = *(const float4*)&dl[wl * 68 + c0];
        float t0 = dv.x + biasl[c0];
        float t1 = dv.y + biasl[c0 + 1];
        float t2 = dv.z + biasl[c0 + 2];
        float t3 = dv.w + biasl[c0 + 3];
        float pr = fmaxf(t0, 0.f) * wgl[c0] + fmaxf(t1, 0.f) * wgl[c0 + 1] +
                   fmaxf(t2, 0.f) * wgl[c0 + 2] + fmaxf(t3, 0.f) * wgl[c0 + 3];
        pr += __shfl_xor(pr, 1, 64);
        pr += __shfl_xor(pr, 2, 64);
        pr += __shfl_xor(pr, 4, 64);
        pr += __shfl_xor(pr, 8, 64);
        if (p == 0) res[wl] = pr + bg[0];
        __syncthreads();
        if (tid < 16) {
            float v = res[tid];
            out[gb * 16 + tid] = v > 0.f ? v : 0.01f * v;
        }
    }
}

// ---------------------------------------------------------------------------
extern "C" void kernel_launch(void* const* d_in, const int* in_sizes, int n_in,
                              void* d_out, int out_size, void* d_ws, size_t ws_size,
                              hipStream_t stream)
{
    const float* x_sites    = (const float*)d_in[0];
    const float* x_wells    = (const float*)d_in[1];
    const int*   e_sw_src   = (const int*)d_in[2];
    const int*   e_sw_dst   = (const int*)d_in[3];
    const int*   e_ws_src   = (const int*)d_in[4];
    const int*   e_ws_dst   = (const int*)d_in[5];
    const float* W_sw       = (const float*)d_in[6];
    const float* att_src_sw = (const float*)d_in[7];
    const float* att_dst_sw = (const float*)d_in[8];
    const float* b_sw       = (const float*)d_in[9];
    const float* Wl_ws      = (const float*)d_in[10];
    const float* bl_ws      = (const float*)d_in[11];
    const float* Wr_ws      = (const float*)d_in[12];
    const float* W_ss       = (const float*)d_in[13];
    // d_in[14], d_in[15]: att_*_ss cancel (softmax over single self edge == 1)
    const float* b_ss       = (const float*)d_in[16];
    const float* Wl_ww      = (const float*)d_in[17];
    const float* bl_ww      = (const float*)d_in[18];
    const float* Wr_ww      = (const float*)d_in[19];
    const float* Wg         = (const float*)d_in[20];
    const float* bg         = (const float*)d_in[21];
    const float* Wsit       = (const float*)d_in[22];
    const float* bsit       = (const float*)d_in[23];
    float* out = (float*)d_out;

    // workspace layout
    unsigned short* xbf = (unsigned short*)d_ws;           // NS*64 bf16
    float* al_s = (float*)(xbf + (size_t)NS_ * 64);        // NS*4
    float* vd   = al_s + (size_t)NS_ * 4;                  // 256
    float* vs   = vd + 256;                                // 256
    u32x4_t* fw = (u32x4_t*)(vs + 256);                    // 512  (8 KB)
    u32x4_t* fs = fw + 512;                                // 1024 (16 KB)
    u32x4_t* fgw= fs + 1024;                               // 2048 (32 KB)
    int* ip     = (int*)(fgw + 2048);
    int* h_sw   = ip;                                      // NW   (zeroed)
    int* h_ws   = h_sw + NW_;                              // NS   (zeroed, adjacent)
    int* rp_sw  = h_ws + NS_;                              // NW+4
    int* cur_sw = rp_sw + NW_ + 4;                         // NW
    int* csr_sw = cur_sw + NW_;                            // E
    int* bs_sw  = csr_sw + NE_;                            // 256
    int* rp_ws  = bs_sw + 256;                             // NS+4
    int* cur_ws = rp_ws + NS_ + 4;                         // NS
    int* csr_ws = cur_ws + NS_;                            // E
    int* bs_ws  = csr_ws + NE_;                            // 256

    hipMemsetAsync(h_sw, 0, (size_t)(NW_ + NS_) * sizeof(int), stream);

    const int nb_sw = (NW_ + EPB - 1) / EPB;   // 196
    const int nb_ws = (NS_ + EPB - 1) / EPB;   // 49

    hipLaunchKernelGGL(k_prep, dim3(15), dim3(256), 0, stream,
                       W_sw, att_src_sw, att_dst_sw, Wl_ww, Wr_ww, Wl_ws, Wr_ws, W_ss,
                       vd, vs, fw, fs, fgw);

    // merged: sites_al + histogram
    hipLaunchKernelGGL(k_hist_sal, dim3(SAL_BLKS + 2 * EGRID), dim3(256), 0, stream,
                       x_sites, vs, xbf, al_s, e_sw_dst, h_sw, e_ws_dst, h_ws);

    hipLaunchKernelGGL(k_scan1_2, dim3(nb_sw + nb_ws), dim3(256), 0, stream,
                       h_sw, NW_, bs_sw, nb_sw, h_ws, NS_, bs_ws);
    hipLaunchKernelGGL(k_scan3m, dim3(nb_sw + nb_ws), dim3(256), 0, stream,
                       h_sw, NW_, bs_sw, rp_sw, cur_sw, nb_sw,
                       h_ws, NS_, bs_ws, rp_ws, cur_ws, nb_ws);
    hipLaunchKernelGGL(k_scatter2, dim3(EGRID, 2), dim3(256), 0, stream,
                       e_sw_src, e_sw_dst, cur_sw, csr_sw,
                       e_ws_src, e_ws_dst, cur_ws, csr_ws);

    hipLaunchKernelGGL(k_fin, dim3(SAGE_BLKS + GAT_BLKS), dim3(256), 0, stream,
                       x_sites, x_wells, rp_ws, csr_ws, fs, bl_ws, b_ss, Wsit, bsit,
                       vd, rp_sw, csr_sw, al_s, xbf, b_sw, bl_ww, fw, fgw,
                       Wg, bg, out);
}